// Round 2
// baseline (320.849 us; speedup 1.0000x reference)
//
#include <hip/hip_runtime.h>
#include <hip/hip_bf16.h>
#include <cstdint>

typedef unsigned short u16;
typedef unsigned int   u32;
typedef __bf16  bf16x8 __attribute__((ext_vector_type(8)));
typedef float   f32x4  __attribute__((ext_vector_type(4)));
typedef unsigned short u16x8 __attribute__((ext_vector_type(8)));

#define GLB(p) ((__attribute__((address_space(1))) void*)(p))
#define LDSP(p) ((__attribute__((address_space(3))) void*)(p))

__device__ __forceinline__ u16 f2bf(float f) {
  u32 u = __builtin_bit_cast(u32, f);
  u32 r = u + 0x7fffu + ((u >> 16) & 1u);
  return (u16)(r >> 16);
}

// ---------------- f32 -> bf16 convert (8 elems/thread) ----------------
__global__ __launch_bounds__(256) void cvt_bf16(const float* __restrict__ in,
                                                u16* __restrict__ out, int n) {
  int i = (blockIdx.x * 256 + threadIdx.x) * 8;
  if (i >= n) return;
  f32x4 a = *(const f32x4*)(in + i);
  f32x4 b = *(const f32x4*)(in + i + 4);
  u16x8 o;
#pragma unroll
  for (int j = 0; j < 4; ++j) { o[j] = f2bf(a[j]); o[4 + j] = f2bf(b[j]); }
  *(u16x8*)(out + i) = o;
}

// ---------------- GEMM C = A * B^T (+bias), bf16 MFMA ----------------
// A: [M][K] bf16 row-major, B: [N][K] bf16 row-major (i.e. B^T input)
// mode 0: Cf[row*N+col] = acc + bias[col]              (f32 out)
// mode 1: pack into qkv [sect][b][h][t][d] bf16, sect=col/1024
__global__ __launch_bounds__(256) void gemm_bt(
    const u16* __restrict__ A, const u16* __restrict__ B,
    const float* __restrict__ bias,
    float* __restrict__ Cf, u16* __restrict__ Cq,
    int M, int N, int K, int mode) {
  __shared__ char lds[32768];
  char* ldsA = lds;
  char* ldsB = lds + 16384;
  const int tid  = threadIdx.x;
  const int lane = tid & 63;
  const int wave = tid >> 6;
  const int m0 = blockIdx.y * 128;
  const int n0 = blockIdx.x * 128;
  const int wr = (wave >> 1) * 64;
  const int wc = (wave & 1) * 64;

  // staging source pointers (pre-swizzled: linear LDS chunk c holds logical
  // chunk c ^ (row&7); reads XOR the same pattern back)
  const u16* gA[4];
  const u16* gB[4];
#pragma unroll
  for (int it = 0; it < 4; ++it) {
    int c  = it * 256 + tid;
    int r  = c >> 3;
    int ch = (c & 7) ^ (r & 7);
    gA[it] = A + (size_t)(m0 + r) * K + ch * 8;
    gB[it] = B + (size_t)(n0 + r) * K + ch * 8;
  }

  f32x4 acc[4][4] = {};

  const int arow  = wr + (lane & 15);
  const int brow  = wc + (lane & 15);
  const int kswz  = (lane & 7) << 4;
  const int kbyte = (lane >> 4) * 16;   // k-offset bytes within 128B row

  for (int kk = 0; kk < K; kk += 64) {
    __syncthreads();
#pragma unroll
    for (int it = 0; it < 4; ++it) {
      int c = it * 256 + tid;
      __builtin_amdgcn_global_load_lds(GLB(gA[it] + kk), LDSP(ldsA + c * 16), 16, 0, 0);
      __builtin_amdgcn_global_load_lds(GLB(gB[it] + kk), LDSP(ldsB + c * 16), 16, 0, 0);
    }
    __syncthreads();
#pragma unroll
    for (int s = 0; s < 2; ++s) {
      bf16x8 af[4], bfr[4];
#pragma unroll
      for (int i = 0; i < 4; ++i)
        af[i] = *(const bf16x8*)(ldsA + (arow + i * 16) * 128 + ((kbyte + s * 64) ^ kswz));
#pragma unroll
      for (int j = 0; j < 4; ++j)
        bfr[j] = *(const bf16x8*)(ldsB + (brow + j * 16) * 128 + ((kbyte + s * 64) ^ kswz));
#pragma unroll
      for (int i = 0; i < 4; ++i)
#pragma unroll
        for (int j = 0; j < 4; ++j)
          acc[i][j] = __builtin_amdgcn_mfma_f32_16x16x32_bf16(af[i], bfr[j], acc[i][j], 0, 0, 0);
    }
  }

  const int r0 = m0 + wr + (lane >> 4) * 4;
  const int c0 = n0 + wc + (lane & 15);
#pragma unroll
  for (int i = 0; i < 4; ++i) {
#pragma unroll
    for (int j = 0; j < 4; ++j) {
      int col  = c0 + j * 16;
      float bv = bias[col];
#pragma unroll
      for (int r = 0; r < 4; ++r) {
        int row = r0 + i * 16 + r;
        float v = acc[i][j][r] + bv;
        if (mode == 0) {
          Cf[(size_t)row * N + col] = v;
        } else {
          int sect = col >> 10, rem = col & 1023;
          int hh = rem >> 6, dd = rem & 63;
          int bb = row >> 11, tt = row & 2047;
          Cq[((((size_t)sect * 4 + bb) * 16 + hh) * 2048 + tt) * 64 + dd] = f2bf(v);
        }
      }
    }
  }
}

// ---------------- V transpose: [bh][t][d] -> [bh][d][t] ----------------
__global__ __launch_bounds__(256) void transv(const u16* __restrict__ Vp,
                                              u16* __restrict__ Vt) {
  __shared__ u16 tl[64][68];
  const int tid = threadIdx.x;
  const int bh  = blockIdx.y;
  const int t0  = blockIdx.x * 64;
  const u16* src = Vp + ((size_t)bh * 2048 + t0) * 64;
#pragma unroll
  for (int it = 0; it < 2; ++it) {
    int c = it * 256 + tid;
    int r = c >> 3, ch = c & 7;
    u16x8 v = *(const u16x8*)(src + r * 64 + ch * 8);
#pragma unroll
    for (int j = 0; j < 8; ++j) tl[r][ch * 8 + j] = v[j];
  }
  __syncthreads();
  u16* dst = Vt + (size_t)bh * 64 * 2048 + t0;
#pragma unroll
  for (int it = 0; it < 2; ++it) {
    int c = it * 256 + tid;
    int d = c >> 3, ch = c & 7;
    u16x8 v;
#pragma unroll
    for (int j = 0; j < 8; ++j) v[j] = tl[ch * 8 + j][d];
    *(u16x8*)(dst + (size_t)d * 2048 + ch * 8) = v;
  }
}

// ---------------- flash attention fwd ----------------
// Qp,Kp: [bh][t][64] bf16; Vt: [bh][64][t] bf16; mask: [b][T] f32 (additive per key)
// AO: [b*T][1024] bf16  (attn output packed back to [t][e] for out-proj GEMM)
__global__ __launch_bounds__(256) void attn_fwd(
    const u16* __restrict__ Qp, const u16* __restrict__ Kp,
    const u16* __restrict__ Vt, const float* __restrict__ mask,
    u16* __restrict__ AO) {
  __shared__ char lds[32768];
  char* ldsQ = lds;
  char* ldsK = lds + 8192;
  char* ldsV = lds + 16384;
  char* ldsP = lds + 24576;
  const int tid  = threadIdx.x;
  const int lane = tid & 63;
  const int wave = tid >> 6;
  const int bh = blockIdx.y;
  const int b  = bh >> 4;
  const int h  = bh & 15;
  const int q0 = blockIdx.x * 64;

  const u16* Qbase = Qp + ((size_t)bh * 2048 + q0) * 64;
  const u16* Kbase = Kp + (size_t)bh * 2048 * 64;
  const u16* Vbase = Vt + (size_t)bh * 64 * 2048;

#pragma unroll
  for (int it = 0; it < 2; ++it) {
    int c = it * 256 + tid;
    int r = c >> 3;
    int ch = (c & 7) ^ (r & 7);
    __builtin_amdgcn_global_load_lds(GLB(Qbase + r * 64 + ch * 8), LDSP(ldsQ + c * 16), 16, 0, 0);
  }

  f32x4 oacc[4] = {};
  float mrun[4] = {-1e30f, -1e30f, -1e30f, -1e30f};
  float lrun[4] = {0.f, 0.f, 0.f, 0.f};

  const int kswz  = (lane & 7) << 4;
  const int kbyte = (lane >> 4) * 16;

  __syncthreads();

  bf16x8 qa[2];
  {
    int qrow = wave * 16 + (lane & 15);
#pragma unroll
    for (int s = 0; s < 2; ++s)
      qa[s] = *(const bf16x8*)(ldsQ + qrow * 128 + ((kbyte + s * 64) ^ kswz));
  }

  const float* mrow = mask + (size_t)b * 2048;

  for (int kv = 0; kv < 2048; kv += 64) {
#pragma unroll
    for (int it = 0; it < 2; ++it) {
      int c = it * 256 + tid;
      int r = c >> 3;
      int ch = (c & 7) ^ (r & 7);
      __builtin_amdgcn_global_load_lds(GLB(Kbase + (size_t)(kv + r) * 64 + ch * 8),
                                       LDSP(ldsK + c * 16), 16, 0, 0);
      __builtin_amdgcn_global_load_lds(GLB(Vbase + (size_t)r * 2048 + kv + ch * 8),
                                       LDSP(ldsV + c * 16), 16, 0, 0);
    }
    __syncthreads();

    // S = Q K^T  (each wave: its 16 q-rows x 64 keys)
    f32x4 sv[4] = {};
#pragma unroll
    for (int j = 0; j < 4; ++j) {
#pragma unroll
      for (int s = 0; s < 2; ++s) {
        bf16x8 kb = *(const bf16x8*)(ldsK + (j * 16 + (lane & 15)) * 128 + ((kbyte + s * 64) ^ kswz));
        sv[j] = __builtin_amdgcn_mfma_f32_16x16x32_bf16(qa[s], kb, sv[j], 0, 0, 0);
      }
    }

    float mk[4];
#pragma unroll
    for (int j = 0; j < 4; ++j) mk[j] = mrow[kv + j * 16 + (lane & 15)];
#pragma unroll
    for (int j = 0; j < 4; ++j)
#pragma unroll
      for (int r = 0; r < 4; ++r)
        sv[j][r] = sv[j][r] * 0.125f + mk[j];

    // online softmax: rows r owned by this lane group (16 lanes share 4 rows)
    float sc[4];
#pragma unroll
    for (int r = 0; r < 4; ++r) {
      float mx = fmaxf(fmaxf(sv[0][r], sv[1][r]), fmaxf(sv[2][r], sv[3][r]));
#pragma unroll
      for (int off = 1; off < 16; off <<= 1)
        mx = fmaxf(mx, __shfl_xor(mx, off, 64));
      float mn = fmaxf(mrun[r], mx);
      sc[r] = __expf(mrun[r] - mn);
      mrun[r] = mn;
    }
    float rs[4] = {0.f, 0.f, 0.f, 0.f};
#pragma unroll
    for (int j = 0; j < 4; ++j)
#pragma unroll
      for (int r = 0; r < 4; ++r) {
        float p = __expf(sv[j][r] - mrun[r]);
        sv[j][r] = p;
        rs[r] += p;
      }
#pragma unroll
    for (int r = 0; r < 4; ++r) {
#pragma unroll
      for (int off = 1; off < 16; off <<= 1)
        rs[r] += __shfl_xor(rs[r], off, 64);
      lrun[r] = lrun[r] * sc[r] + rs[r];
    }
#pragma unroll
    for (int n = 0; n < 4; ++n)
#pragma unroll
      for (int r = 0; r < 4; ++r)
        oacc[n][r] *= sc[r];

    // P -> LDS (bf16, swizzled), per-wave region; wave-internal so no barrier
    char* pb = ldsP + wave * 2048;
#pragma unroll
    for (int j = 0; j < 4; ++j)
#pragma unroll
      for (int r = 0; r < 4; ++r) {
        int prow = (lane >> 4) * 4 + r;
        int pcol = j * 16 + (lane & 15);
        *(u16*)(pb + prow * 128 + ((pcol * 2) ^ ((prow & 7) << 4))) = f2bf(sv[j][r]);
      }

    bf16x8 pa[2];
#pragma unroll
    for (int s = 0; s < 2; ++s)
      pa[s] = *(const bf16x8*)(pb + (lane & 15) * 128 + ((kbyte + s * 64) ^ kswz));
#pragma unroll
    for (int n = 0; n < 4; ++n) {
#pragma unroll
      for (int s = 0; s < 2; ++s) {
        bf16x8 vb = *(const bf16x8*)(ldsV + (n * 16 + (lane & 15)) * 128 + ((kbyte + s * 64) ^ kswz));
        oacc[n] = __builtin_amdgcn_mfma_f32_16x16x32_bf16(pa[s], vb, oacc[n], 0, 0, 0);
      }
    }
    __syncthreads();
  }

#pragma unroll
  for (int r = 0; r < 4; ++r) {
    float inv = 1.0f / lrun[r];
    int t = q0 + wave * 16 + (lane >> 4) * 4 + r;
#pragma unroll
    for (int n = 0; n < 4; ++n) {
      int e = h * 64 + n * 16 + (lane & 15);
      AO[((size_t)b * 2048 + t) * 1024 + e] = f2bf(oacc[n][r] * inv);
    }
  }
}

// ---------------- launch ----------------
extern "C" void kernel_launch(void* const* d_in, const int* in_sizes, int n_in,
                              void* d_out, int out_size, void* d_ws, size_t ws_size,
                              hipStream_t stream) {
  const float* x     = (const float*)d_in[0];   // [4,2048,1024]
  const float* mask  = (const float*)d_in[1];   // [4,2048]
  const float* w_in  = (const float*)d_in[2];   // [3072,1024]
  const float* b_in  = (const float*)d_in[3];   // [3072]
  const float* w_out = (const float*)d_in[4];   // [1024,1024]
  const float* b_out = (const float*)d_in[5];   // [1024]
  float* out = (float*)d_out;                   // [4,2048,1024]

  u16* xbf  = (u16*)d_ws;                         // 8192*1024
  u16* wbf  = xbf  + (size_t)8192 * 1024;         // 3072*1024
  u16* owbf = wbf  + (size_t)3072 * 1024;         // 1024*1024
  u16* qkvp = owbf + (size_t)1024 * 1024;         // 3*8192*1024 packed [s][b][h][t][d]
  u16* vt   = qkvp + (size_t)3 * 8192 * 1024;     // 8192*1024  [bh][d][t]
  u16* ao   = vt   + (size_t)8192 * 1024;         // 8192*1024  [b*t][e]

  cvt_bf16<<<4096, 256, 0, stream>>>(x, xbf, 8388608);
  cvt_bf16<<<1536, 256, 0, stream>>>(w_in, wbf, 3145728);
  cvt_bf16<<<512, 256, 0, stream>>>(w_out, owbf, 1048576);

  gemm_bt<<<dim3(24, 64), 256, 0, stream>>>(xbf, wbf, b_in, nullptr, qkvp,
                                            8192, 3072, 1024, 1);
  transv<<<dim3(32, 64), 256, 0, stream>>>(qkvp + (size_t)2 * 8192 * 1024, vt);
  attn_fwd<<<dim3(32, 64), 256, 0, stream>>>(qkvp, qkvp + (size_t)8192 * 1024,
                                             vt, mask, ao);
  gemm_bt<<<dim3(8, 64), 256, 0, stream>>>(ao, owbf, b_out, out, nullptr,
                                           8192, 1024, 1024, 0);
}

// Round 3
// 259.215 us; speedup vs baseline: 1.2378x; 1.2378x over previous
//
#include <hip/hip_runtime.h>
#include <hip/hip_bf16.h>
#include <cstdint>

typedef unsigned short u16;
typedef unsigned int   u32;
typedef __bf16  bf16x8 __attribute__((ext_vector_type(8)));
typedef __bf16  bf16x2 __attribute__((ext_vector_type(2)));
typedef float   f32x4  __attribute__((ext_vector_type(4)));
typedef unsigned short u16x8 __attribute__((ext_vector_type(8)));
typedef unsigned int   u32x2 __attribute__((ext_vector_type(2)));

#define GLB(p) ((__attribute__((address_space(1))) void*)(p))
#define LDSP(p) ((__attribute__((address_space(3))) void*)(p))

__device__ __forceinline__ u16 f2bf(float f) {
  u32 u = __builtin_bit_cast(u32, f);
  u32 r = u + 0x7fffu + ((u >> 16) & 1u);
  return (u16)(r >> 16);
}

// ---------------- f32 -> bf16 convert (8 elems/thread) ----------------
__global__ __launch_bounds__(256) void cvt_bf16(const float* __restrict__ in,
                                                u16* __restrict__ out, int n) {
  int i = (blockIdx.x * 256 + threadIdx.x) * 8;
  if (i >= n) return;
  f32x4 a = *(const f32x4*)(in + i);
  f32x4 b = *(const f32x4*)(in + i + 4);
  u16x8 o;
#pragma unroll
  for (int j = 0; j < 4; ++j) { o[j] = f2bf(a[j]); o[4 + j] = f2bf(b[j]); }
  *(u16x8*)(out + i) = o;
}

// ---------------- GEMM C = A * B^T (+bias), bf16 MFMA ----------------
__global__ __launch_bounds__(256) void gemm_bt(
    const u16* __restrict__ A, const u16* __restrict__ B,
    const float* __restrict__ bias,
    float* __restrict__ Cf, u16* __restrict__ Cq,
    int M, int N, int K, int mode) {
  __shared__ char lds[32768];
  char* ldsA = lds;
  char* ldsB = lds + 16384;
  const int tid  = threadIdx.x;
  const int lane = tid & 63;
  const int wave = tid >> 6;
  const int m0 = blockIdx.y * 128;
  const int n0 = blockIdx.x * 128;
  const int wr = (wave >> 1) * 64;
  const int wc = (wave & 1) * 64;

  const u16* gA[4];
  const u16* gB[4];
#pragma unroll
  for (int it = 0; it < 4; ++it) {
    int c  = it * 256 + tid;
    int r  = c >> 3;
    int ch = (c & 7) ^ (r & 7);
    gA[it] = A + (size_t)(m0 + r) * K + ch * 8;
    gB[it] = B + (size_t)(n0 + r) * K + ch * 8;
  }

  f32x4 acc[4][4] = {};

  const int arow  = wr + (lane & 15);
  const int brow  = wc + (lane & 15);
  const int kswz  = (lane & 7) << 4;
  const int kbyte = (lane >> 4) * 16;

  for (int kk = 0; kk < K; kk += 64) {
    __syncthreads();
#pragma unroll
    for (int it = 0; it < 4; ++it) {
      int c = it * 256 + tid;
      __builtin_amdgcn_global_load_lds(GLB(gA[it] + kk), LDSP(ldsA + c * 16), 16, 0, 0);
      __builtin_amdgcn_global_load_lds(GLB(gB[it] + kk), LDSP(ldsB + c * 16), 16, 0, 0);
    }
    __syncthreads();
#pragma unroll
    for (int s = 0; s < 2; ++s) {
      bf16x8 af[4], bfr[4];
#pragma unroll
      for (int i = 0; i < 4; ++i)
        af[i] = *(const bf16x8*)(ldsA + (arow + i * 16) * 128 + ((kbyte + s * 64) ^ kswz));
#pragma unroll
      for (int j = 0; j < 4; ++j)
        bfr[j] = *(const bf16x8*)(ldsB + (brow + j * 16) * 128 + ((kbyte + s * 64) ^ kswz));
#pragma unroll
      for (int i = 0; i < 4; ++i)
#pragma unroll
        for (int j = 0; j < 4; ++j)
          acc[i][j] = __builtin_amdgcn_mfma_f32_16x16x32_bf16(af[i], bfr[j], acc[i][j], 0, 0, 0);
    }
  }

  const int r0 = m0 + wr + (lane >> 4) * 4;
  const int c0 = n0 + wc + (lane & 15);
#pragma unroll
  for (int i = 0; i < 4; ++i) {
#pragma unroll
    for (int j = 0; j < 4; ++j) {
      int col  = c0 + j * 16;
      float bv = bias[col];
#pragma unroll
      for (int r = 0; r < 4; ++r) {
        int row = r0 + i * 16 + r;
        float v = acc[i][j][r] + bv;
        if (mode == 0) {
          Cf[(size_t)row * N + col] = v;
        } else {
          int sect = col >> 10, rem = col & 1023;
          int hh = rem >> 6, dd = rem & 63;
          int bb = row >> 11, tt = row & 2047;
          Cq[((((size_t)sect * 4 + bb) * 16 + hh) * 2048 + tt) * 64 + dd] = f2bf(v);
        }
      }
    }
  }
}

// ---------------- V transpose: [bh][t][d] -> [bh][d][t] ----------------
__global__ __launch_bounds__(256) void transv(const u16* __restrict__ Vp,
                                              u16* __restrict__ Vt) {
  __shared__ u16 tl[64][68];
  const int tid = threadIdx.x;
  const int bh  = blockIdx.y;
  const int t0  = blockIdx.x * 64;
  const u16* src = Vp + ((size_t)bh * 2048 + t0) * 64;
#pragma unroll
  for (int it = 0; it < 2; ++it) {
    int c = it * 256 + tid;
    int r = c >> 3, ch = c & 7;
    u16x8 v = *(const u16x8*)(src + r * 64 + ch * 8);
#pragma unroll
    for (int j = 0; j < 8; ++j) tl[r][ch * 8 + j] = v[j];
  }
  __syncthreads();
  u16* dst = Vt + (size_t)bh * 64 * 2048 + t0;
#pragma unroll
  for (int it = 0; it < 2; ++it) {
    int c = it * 256 + tid;
    int d = c >> 3, ch = c & 7;
    u16x8 v;
#pragma unroll
    for (int j = 0; j < 8; ++j) v[j] = tl[ch * 8 + j][d];
    *(u16x8*)(dst + (size_t)d * 2048 + ch * 8) = v;
  }
}

// ---------------- flash attention fwd (swapped QK^T, in-reg softmax) ----
// Qp,Kp: [bh][t][64] bf16; Vt: [bh][64][t] bf16; mask: [b][T] f32
// AO: [b*T][1024] bf16
__global__ __launch_bounds__(256) void attn_fwd(
    const u16* __restrict__ Qp, const u16* __restrict__ Kp,
    const u16* __restrict__ Vt, const float* __restrict__ mask,
    u16* __restrict__ AO) {
  __shared__ char lds[40960];
  char* ldsQ = lds;                 // 8KB  [64 q][64 d] bf16, swizzled
  char* ldsK = lds + 8192;          // 8KB  [64 key][64 d]
  char* ldsV = lds + 16384;         // 8KB  [64 d][64 key]
  char* ldsP = lds + 24576;         // 8KB  4 waves x [16 q][64 key]
  char* ldsM = lds + 32768;         // 8KB  mask*log2e f32[2048]
  const int tid  = threadIdx.x;
  const int lane = tid & 63;
  const int wave = tid >> 6;
  const int g    = lane >> 4;       // 4-lane-group id (key sub-block)
  const int qid  = lane & 15;       // q-row within wave's 16
  const int bh = blockIdx.y;
  const int b  = bh >> 4;
  const int h  = bh & 15;
  const int q0 = blockIdx.x * 64;

  const u16* Qbase = Qp + ((size_t)bh * 2048 + q0) * 64;
  const u16* Kbase = Kp + (size_t)bh * 2048 * 64;
  const u16* Vbase = Vt + (size_t)bh * 64 * 2048;
  const float* mrow = mask + (size_t)b * 2048;

  // stage Q (pre-swizzled source, linear LDS dest)
#pragma unroll
  for (int it = 0; it < 2; ++it) {
    int c = it * 256 + tid;
    int r = c >> 3;
    int ch = (c & 7) ^ (r & 7);
    __builtin_amdgcn_global_load_lds(GLB(Qbase + r * 64 + ch * 8), LDSP(ldsQ + c * 16), 16, 0, 0);
  }
  // stage mask * log2(e) into LDS (read per-tile as f32x4, broadcast per group)
  {
    const float LOG2E = 1.4426950408889634f;
    int i = tid * 8;
    f32x4 a = *(const f32x4*)(mrow + i);
    f32x4 bq = *(const f32x4*)(mrow + i + 4);
#pragma unroll
    for (int j = 0; j < 4; ++j) { a[j] *= LOG2E; bq[j] *= LOG2E; }
    *(f32x4*)(ldsM + i * 4) = a;
    *(f32x4*)(ldsM + i * 4 + 16) = bq;
  }

  f32x4 oacc[4] = {};
  float mrun = -1e30f;   // running max, log2 domain, for q-row = qid
  float lrun = 0.f;      // running denom for q-row = qid

  const int kswz  = (lane & 7) << 4;
  const int kbyte = g * 16;
  const int pswz  = (qid & 7) << 4;
  char* pb = ldsP + wave * 2048;

  __syncthreads();

  bf16x8 qa[2];
  {
    int qrow = wave * 16 + qid;
#pragma unroll
    for (int s = 0; s < 2; ++s)
      qa[s] = *(const bf16x8*)(ldsQ + qrow * 128 + ((kbyte + s * 64) ^ kswz));
  }

  const float SC = 0.125f * 1.4426950408889634f;  // 1/sqrt(64) * log2(e)

  for (int kv = 0; kv < 2048; kv += 64) {
#pragma unroll
    for (int it = 0; it < 2; ++it) {
      int c = it * 256 + tid;
      int r = c >> 3;
      int ch = (c & 7) ^ (r & 7);
      __builtin_amdgcn_global_load_lds(GLB(Kbase + (size_t)(kv + r) * 64 + ch * 8),
                                       LDSP(ldsK + c * 16), 16, 0, 0);
      __builtin_amdgcn_global_load_lds(GLB(Vbase + (size_t)r * 2048 + kv + ch * 8),
                                       LDSP(ldsV + c * 16), 16, 0, 0);
    }
    __syncthreads();

    // S^T = K Q^T : lane holds keys {16j+4g+r} of q-row qid
    f32x4 sv[4] = {};
#pragma unroll
    for (int j = 0; j < 4; ++j) {
#pragma unroll
      for (int s = 0; s < 2; ++s) {
        bf16x8 kb = *(const bf16x8*)(ldsK + (j * 16 + qid) * 128 + ((kbyte + s * 64) ^ kswz));
        sv[j] = __builtin_amdgcn_mfma_f32_16x16x32_bf16(kb, qa[s], sv[j], 0, 0, 0);
      }
    }

    // scale to log2 domain + additive mask (per-key, rows of S^T)
#pragma unroll
    for (int j = 0; j < 4; ++j) {
      f32x4 mk = *(const f32x4*)(ldsM + (kv + j * 16 + g * 4) * 4);
#pragma unroll
      for (int r = 0; r < 4; ++r)
        sv[j][r] = sv[j][r] * SC + mk[r];
    }

    // tile max for this q-row (15 in-lane + 2 shfl)
    float pm;
    {
      f32x4 m4;
#pragma unroll
      for (int r = 0; r < 4; ++r)
        m4[r] = fmaxf(fmaxf(sv[0][r], sv[1][r]), fmaxf(sv[2][r], sv[3][r]));
      pm = fmaxf(fmaxf(m4[0], m4[1]), fmaxf(m4[2], m4[3]));
      pm = fmaxf(pm, __shfl_xor(pm, 16, 64));
      pm = fmaxf(pm, __shfl_xor(pm, 32, 64));
    }

    // defer-max (T13): only rescale when max grew past threshold (log2 dom.)
    if (!__all(pm <= mrun + 8.f)) {
      float mnew = fmaxf(mrun, pm);
      float sc = exp2f(mrun - mnew);
      mrun = mnew;
      lrun *= sc;
      int gb = 20 * g;  // lane (16g + 4g + r) holds sc for q-row 4g+r
#pragma unroll
      for (int r = 0; r < 4; ++r) {
        float scr = __shfl(sc, gb + r, 64);
#pragma unroll
        for (int n = 0; n < 4; ++n) oacc[n][r] *= scr;
      }
    }

    // P = exp2(S' - m), row sum
    float rs = 0.f;
#pragma unroll
    for (int j = 0; j < 4; ++j)
#pragma unroll
      for (int r = 0; r < 4; ++r) {
        float p = exp2f(sv[j][r] - mrun);
        sv[j][r] = p;
        rs += p;
      }
    rs += __shfl_xor(rs, 16, 64);
    rs += __shfl_xor(rs, 32, 64);
    lrun += rs;

    // pack P -> per-wave LDS row qid (keys 16j+4g..+3), XOR-swizzled b64
#pragma unroll
    for (int j = 0; j < 4; ++j) {
      bf16x2 lo = {(__bf16)sv[j][0], (__bf16)sv[j][1]};
      bf16x2 hi = {(__bf16)sv[j][2], (__bf16)sv[j][3]};
      u32x2 w;
      w[0] = __builtin_bit_cast(u32, lo);
      w[1] = __builtin_bit_cast(u32, hi);
      *(u32x2*)(pb + qid * 128 + ((32 * j + 8 * g) ^ pswz)) = w;
    }

    // PA fragment: row=qid, keys s*32 + 8g..+7 (b128, same swizzle)
    bf16x8 pa[2];
#pragma unroll
    for (int s = 0; s < 2; ++s)
      pa[s] = *(const bf16x8*)(pb + qid * 128 + ((s * 64 + 16 * g) ^ pswz));
#pragma unroll
    for (int n = 0; n < 4; ++n) {
#pragma unroll
      for (int s = 0; s < 2; ++s) {
        bf16x8 vb = *(const bf16x8*)(ldsV + (n * 16 + qid) * 128 + ((kbyte + s * 64) ^ kswz));
        oacc[n] = __builtin_amdgcn_mfma_f32_16x16x32_bf16(pa[s], vb, oacc[n], 0, 0, 0);
      }
    }
    __syncthreads();
  }

  // epilogue: per-lane lrun is for q-row qid; broadcast to oacc rows 4g+r
  float linv = 1.0f / lrun;
  int gb = 20 * g;
#pragma unroll
  for (int r = 0; r < 4; ++r) {
    float inv = __shfl(linv, gb + r, 64);
    int t = q0 + wave * 16 + g * 4 + r;
#pragma unroll
    for (int n = 0; n < 4; ++n) {
      int e = h * 64 + n * 16 + qid;
      AO[((size_t)b * 2048 + t) * 1024 + e] = f2bf(oacc[n][r] * inv);
    }
  }
}

// ---------------- launch ----------------
extern "C" void kernel_launch(void* const* d_in, const int* in_sizes, int n_in,
                              void* d_out, int out_size, void* d_ws, size_t ws_size,
                              hipStream_t stream) {
  const float* x     = (const float*)d_in[0];
  const float* mask  = (const float*)d_in[1];
  const float* w_in  = (const float*)d_in[2];
  const float* b_in  = (const float*)d_in[3];
  const float* w_out = (const float*)d_in[4];
  const float* b_out = (const float*)d_in[5];
  float* out = (float*)d_out;

  u16* xbf  = (u16*)d_ws;
  u16* wbf  = xbf  + (size_t)8192 * 1024;
  u16* owbf = wbf  + (size_t)3072 * 1024;
  u16* qkvp = owbf + (size_t)1024 * 1024;
  u16* vt   = qkvp + (size_t)3 * 8192 * 1024;
  u16* ao   = vt   + (size_t)8192 * 1024;

  cvt_bf16<<<4096, 256, 0, stream>>>(x, xbf, 8388608);
  cvt_bf16<<<1536, 256, 0, stream>>>(w_in, wbf, 3145728);
  cvt_bf16<<<512, 256, 0, stream>>>(w_out, owbf, 1048576);

  gemm_bt<<<dim3(24, 64), 256, 0, stream>>>(xbf, wbf, b_in, nullptr, qkvp,
                                            8192, 3072, 1024, 1);
  transv<<<dim3(32, 64), 256, 0, stream>>>(qkvp + (size_t)2 * 8192 * 1024, vt);
  attn_fwd<<<dim3(32, 64), 256, 0, stream>>>(qkvp, qkvp + (size_t)8192 * 1024,
                                             vt, mask, ao);
  gemm_bt<<<dim3(8, 64), 256, 0, stream>>>(ao, owbf, b_out, out, nullptr,
                                           8192, 1024, 1024, 0);
}

// Round 4
// 241.715 us; speedup vs baseline: 1.3274x; 1.0724x over previous
//
#include <hip/hip_runtime.h>
#include <hip/hip_bf16.h>
#include <cstdint>

typedef unsigned short u16;
typedef unsigned int   u32;
typedef __bf16  bf16x8 __attribute__((ext_vector_type(8)));
typedef __bf16  bf16x2 __attribute__((ext_vector_type(2)));
typedef float   f32x4  __attribute__((ext_vector_type(4)));
typedef unsigned short u16x8 __attribute__((ext_vector_type(8)));
typedef unsigned int   u32x2 __attribute__((ext_vector_type(2)));
typedef unsigned int   u32x4 __attribute__((ext_vector_type(4)));

#define GLB(p) ((__attribute__((address_space(1))) void*)(p))
#define LDSP(p) ((__attribute__((address_space(3))) void*)(p))

__device__ __forceinline__ u16 f2bf(float f) {
  u32 u = __builtin_bit_cast(u32, f);
  u32 r = u + 0x7fffu + ((u >> 16) & 1u);
  return (u16)(r >> 16);
}

// ---------------- f32 -> bf16 convert (8 elems/thread) ----------------
__global__ __launch_bounds__(256) void cvt_bf16(const float* __restrict__ in,
                                                u16* __restrict__ out, int n) {
  int i = (blockIdx.x * 256 + threadIdx.x) * 8;
  if (i >= n) return;
  f32x4 a = *(const f32x4*)(in + i);
  f32x4 b = *(const f32x4*)(in + i + 4);
  u16x8 o;
#pragma unroll
  for (int j = 0; j < 4; ++j) { o[j] = f2bf(a[j]); o[4 + j] = f2bf(b[j]); }
  *(u16x8*)(out + i) = o;
}

// ---------------- mask pre-scale: out = in * log2(e) ----------------
__global__ __launch_bounds__(256) void scale_mask(const float* __restrict__ in,
                                                  float* __restrict__ out, int n) {
  int i = blockIdx.x * 256 + threadIdx.x;
  if (i < n) out[i] = in[i] * 1.4426950408889634f;
}

// ---------------- GEMM C = A * B^T (+bias), bf16 MFMA ----------------
__global__ __launch_bounds__(256) void gemm_bt(
    const u16* __restrict__ A, const u16* __restrict__ B,
    const float* __restrict__ bias,
    float* __restrict__ Cf, u16* __restrict__ Cq,
    int M, int N, int K, int mode) {
  __shared__ char lds[32768];
  char* ldsA = lds;
  char* ldsB = lds + 16384;
  const int tid  = threadIdx.x;
  const int lane = tid & 63;
  const int wave = tid >> 6;
  const int m0 = blockIdx.y * 128;
  const int n0 = blockIdx.x * 128;
  const int wr = (wave >> 1) * 64;
  const int wc = (wave & 1) * 64;

  const u16* gA[4];
  const u16* gB[4];
#pragma unroll
  for (int it = 0; it < 4; ++it) {
    int c  = it * 256 + tid;
    int r  = c >> 3;
    int ch = (c & 7) ^ (r & 7);
    gA[it] = A + (size_t)(m0 + r) * K + ch * 8;
    gB[it] = B + (size_t)(n0 + r) * K + ch * 8;
  }

  f32x4 acc[4][4] = {};

  const int arow  = wr + (lane & 15);
  const int brow  = wc + (lane & 15);
  const int kswz  = (lane & 7) << 4;
  const int kbyte = (lane >> 4) * 16;

  for (int kk = 0; kk < K; kk += 64) {
    __syncthreads();
#pragma unroll
    for (int it = 0; it < 4; ++it) {
      int c = it * 256 + tid;
      __builtin_amdgcn_global_load_lds(GLB(gA[it] + kk), LDSP(ldsA + c * 16), 16, 0, 0);
      __builtin_amdgcn_global_load_lds(GLB(gB[it] + kk), LDSP(ldsB + c * 16), 16, 0, 0);
    }
    __syncthreads();
#pragma unroll
    for (int s = 0; s < 2; ++s) {
      bf16x8 af[4], bfr[4];
#pragma unroll
      for (int i = 0; i < 4; ++i)
        af[i] = *(const bf16x8*)(ldsA + (arow + i * 16) * 128 + ((kbyte + s * 64) ^ kswz));
#pragma unroll
      for (int j = 0; j < 4; ++j)
        bfr[j] = *(const bf16x8*)(ldsB + (brow + j * 16) * 128 + ((kbyte + s * 64) ^ kswz));
#pragma unroll
      for (int i = 0; i < 4; ++i)
#pragma unroll
        for (int j = 0; j < 4; ++j)
          acc[i][j] = __builtin_amdgcn_mfma_f32_16x16x32_bf16(af[i], bfr[j], acc[i][j], 0, 0, 0);
    }
  }

  const int r0 = m0 + wr + (lane >> 4) * 4;
  const int c0 = n0 + wc + (lane & 15);
#pragma unroll
  for (int i = 0; i < 4; ++i) {
#pragma unroll
    for (int j = 0; j < 4; ++j) {
      int col  = c0 + j * 16;
      float bv = bias[col];
#pragma unroll
      for (int r = 0; r < 4; ++r) {
        int row = r0 + i * 16 + r;
        float v = acc[i][j][r] + bv;
        if (mode == 0) {
          Cf[(size_t)row * N + col] = v;
        } else {
          int sect = col >> 10, rem = col & 1023;
          int hh = rem >> 6, dd = rem & 63;
          int bb = row >> 11, tt = row & 2047;
          Cq[((((size_t)sect * 4 + bb) * 16 + hh) * 2048 + tt) * 64 + dd] = f2bf(v);
        }
      }
    }
  }
}

// ---------------- V transpose: [bh][t][d] -> [bh][d][t] ----------------
__global__ __launch_bounds__(256) void transv(const u16* __restrict__ Vp,
                                              u16* __restrict__ Vt) {
  __shared__ u16 tl[64][68];
  const int tid = threadIdx.x;
  const int bh  = blockIdx.y;
  const int t0  = blockIdx.x * 64;
  const u16* src = Vp + ((size_t)bh * 2048 + t0) * 64;
#pragma unroll
  for (int it = 0; it < 2; ++it) {
    int c = it * 256 + tid;
    int r = c >> 3, ch = c & 7;
    u16x8 v = *(const u16x8*)(src + r * 64 + ch * 8);
#pragma unroll
    for (int j = 0; j < 8; ++j) tl[r][ch * 8 + j] = v[j];
  }
  __syncthreads();
  u16* dst = Vt + (size_t)bh * 64 * 2048 + t0;
#pragma unroll
  for (int it = 0; it < 2; ++it) {
    int c = it * 256 + tid;
    int d = c >> 3, ch = c & 7;
    u16x8 v;
#pragma unroll
    for (int j = 0; j < 8; ++j) v[j] = tl[ch * 8 + j][d];
    *(u16x8*)(dst + (size_t)d * 2048 + ch * 8) = v;
  }
}

// ---------------- flash attention fwd ----------------
// Qp,Kp: [bh][t][64] bf16; Vt: [bh][64][t] bf16; maskS: [b][T] f32 (pre-scaled by log2e)
// AO: [b*T][1024] bf16
// LDS: K0 @0, K1 @8192, V0 @16384, V1 @24576, P @32768 (4 waves x 2KB)
__global__ __launch_bounds__(256, 4) void attn_fwd(
    const u16* __restrict__ Qp, const u16* __restrict__ Kp,
    const u16* __restrict__ Vt, const float* __restrict__ maskS,
    u16* __restrict__ AO) {
  __shared__ char lds[40960];
  const int tid  = threadIdx.x;
  const int lane = tid & 63;
  const int wave = tid >> 6;
  const int g    = lane >> 4;
  const int qid  = lane & 15;
  const int bh = blockIdx.y;
  const int b  = bh >> 4;
  const int h  = bh & 15;
  const int q0 = blockIdx.x * 64;

  const u16* Qbase = Qp + ((size_t)bh * 2048 + q0) * 64;
  const u16* Kbase = Kp + (size_t)bh * 2048 * 64;
  const u16* Vbase = Vt + (size_t)bh * 64 * 2048;
  const float* mrowS = maskS + (size_t)b * 2048;

  // staging sources (pre-swizzled: physical chunk c holds logical (c&7)^(r&7))
  const u16* gK[2];
  const u16* gV[2];
  int ldso[2];
#pragma unroll
  for (int it = 0; it < 2; ++it) {
    int c = it * 256 + tid;
    int r = c >> 3;
    int ch = (c & 7) ^ (r & 7);
    gK[it] = Kbase + (size_t)r * 64 + ch * 8;
    gV[it] = Vbase + (size_t)r * 2048 + ch * 8;
    ldso[it] = c * 16;
  }

#define STAGE(SEL, KVV)                                                        \
  do {                                                                         \
    _Pragma("unroll") for (int it = 0; it < 2; ++it) {                         \
      __builtin_amdgcn_global_load_lds(GLB(gK[it] + (size_t)(KVV) * 64),       \
                                       LDSP(lds + (SEL) * 8192 + ldso[it]), 16, 0, 0); \
      __builtin_amdgcn_global_load_lds(GLB(gV[it] + (KVV)),                    \
                                       LDSP(lds + 16384 + (SEL) * 8192 + ldso[it]), 16, 0, 0); \
    }                                                                          \
  } while (0)

#define LOADMASK(DST, KVV)                                                     \
  do {                                                                         \
    _Pragma("unroll") for (int j = 0; j < 4; ++j)                              \
      DST[j] = *(const f32x4*)(mrowS + (KVV) + j * 16 + g * 4);                \
  } while (0)

  // Q fragments straight from global (coalesced 16B/lane)
  bf16x8 qa[2];
  {
    int qrow = wave * 16 + qid;
#pragma unroll
    for (int s = 0; s < 2; ++s)
      qa[s] = __builtin_bit_cast(bf16x8, *(const u16x8*)(Qbase + qrow * 64 + 8 * g + 32 * s));
  }

  f32x4 oacc[4] = {};
  float mrun = -1e30f;   // running max (log2 domain) for q-row = qid
  float lrun = 0.f;      // per-lane partial denom for q-row = qid

  const int kswz = (qid & 7) << 4;
  // P-buffer addressing (conflict-free slot swizzle)
  const int q0b = qid & 1, q1b = (qid >> 1) & 1, q2b = (qid >> 2) & 1, q3b = qid >> 3;
  const int g0 = g & 1, g1 = g >> 1;
  const int pbase = 32768 + wave * 2048 + qid * 128;
  const int ws0  = (q3b ^ g0) | ((q0b ^ g1) << 1) | (q1b << 2) | (q2b << 3);
  const int slo0 = q3b | ((q0b ^ g0) << 1) | ((q1b ^ g1) << 2) | (q2b << 3);
  int pwa[4], pra[4];
#pragma unroll
  for (int j = 0; j < 4; ++j) pwa[j] = pbase + (ws0 ^ (j << 2)) * 8;
#pragma unroll
  for (int s = 0; s < 2; ++s) {
    pra[2 * s]     = pbase + ((slo0 ^ (s << 3))) * 8;
    pra[2 * s + 1] = pbase + ((slo0 ^ (s << 3)) ^ 1) * 8;
  }

  const float SC = 0.125f * 1.4426950408889634f;  // 1/sqrt(64) * log2(e)

#define COMPUTE(SEL, MK)                                                       \
  do {                                                                         \
    f32x4 sv[4] = {};                                                          \
    _Pragma("unroll") for (int j = 0; j < 4; ++j)                              \
      _Pragma("unroll") for (int s = 0; s < 2; ++s) {                          \
        bf16x8 kb = *(const bf16x8*)(lds + (SEL) * 8192 + (j * 16 + qid) * 128 \
                                     + ((g * 16) ^ kswz ^ (s * 64)));          \
        sv[j] = __builtin_amdgcn_mfma_f32_16x16x32_bf16(kb, qa[s], sv[j], 0, 0, 0); \
      }                                                                        \
    _Pragma("unroll") for (int j = 0; j < 4; ++j)                              \
      _Pragma("unroll") for (int r = 0; r < 4; ++r)                            \
        sv[j][r] = sv[j][r] * SC + MK[j][r];                                   \
    float pm;                                                                  \
    {                                                                          \
      f32x4 m4;                                                                \
      _Pragma("unroll") for (int r = 0; r < 4; ++r)                            \
        m4[r] = fmaxf(fmaxf(sv[0][r], sv[1][r]), fmaxf(sv[2][r], sv[3][r]));   \
      pm = fmaxf(fmaxf(m4[0], m4[1]), fmaxf(m4[2], m4[3]));                    \
    }                                                                          \
    if (!__all(pm <= mrun + 8.f)) {                                            \
      pm = fmaxf(pm, __shfl_xor(pm, 16, 64));                                  \
      pm = fmaxf(pm, __shfl_xor(pm, 32, 64));                                  \
      float mnew = fmaxf(mrun, pm);                                            \
      float sc = exp2f(mrun - mnew);                                           \
      mrun = mnew;                                                             \
      lrun *= sc;                                                              \
      _Pragma("unroll") for (int r = 0; r < 4; ++r) {                          \
        float scr = __shfl(sc, 20 * g + r, 64);                                \
        _Pragma("unroll") for (int n = 0; n < 4; ++n) oacc[n][r] *= scr;       \
      }                                                                        \
    }                                                                          \
    float rsum = 0.f;                                                          \
    _Pragma("unroll") for (int j = 0; j < 4; ++j)                              \
      _Pragma("unroll") for (int r = 0; r < 4; ++r) {                          \
        float p = exp2f(sv[j][r] - mrun);                                      \
        sv[j][r] = p;                                                          \
        rsum += p;                                                             \
      }                                                                        \
    lrun += rsum;                                                              \
    _Pragma("unroll") for (int j = 0; j < 4; ++j) {                            \
      bf16x2 lo = {(__bf16)sv[j][0], (__bf16)sv[j][1]};                        \
      bf16x2 hi = {(__bf16)sv[j][2], (__bf16)sv[j][3]};                        \
      u32x2 w;                                                                 \
      w[0] = __builtin_bit_cast(u32, lo);                                      \
      w[1] = __builtin_bit_cast(u32, hi);                                      \
      *(u32x2*)(lds + pwa[j]) = w;                                             \
    }                                                                          \
    bf16x8 pa[2];                                                              \
    _Pragma("unroll") for (int s = 0; s < 2; ++s) {                            \
      u32x2 lo = *(const u32x2*)(lds + pra[2 * s]);                            \
      u32x2 hi = *(const u32x2*)(lds + pra[2 * s + 1]);                        \
      u32x4 pw;                                                                \
      pw[0] = lo[0]; pw[1] = lo[1]; pw[2] = hi[0]; pw[3] = hi[1];              \
      pa[s] = __builtin_bit_cast(bf16x8, pw);                                  \
    }                                                                          \
    _Pragma("unroll") for (int n = 0; n < 4; ++n)                              \
      _Pragma("unroll") for (int s = 0; s < 2; ++s) {                          \
        bf16x8 vb = *(const bf16x8*)(lds + 16384 + (SEL) * 8192                \
                                     + (n * 16 + qid) * 128                    \
                                     + ((g * 16) ^ kswz ^ (s * 64)));          \
        oacc[n] = __builtin_amdgcn_mfma_f32_16x16x32_bf16(pa[s], vb, oacc[n], 0, 0, 0); \
      }                                                                        \
  } while (0)

  f32x4 m0[4], m1[4];
  STAGE(0, 0);
  LOADMASK(m0, 0);
  __syncthreads();

  for (int kv = 0; kv < 2048; kv += 128) {
    if (kv + 64 < 2048) { STAGE(1, kv + 64); LOADMASK(m1, kv + 64); }
    COMPUTE(0, m0);
    __syncthreads();
    if (kv + 128 < 2048) { STAGE(0, kv + 128); LOADMASK(m0, kv + 128); }
    COMPUTE(1, m1);
    __syncthreads();
  }

  // epilogue: finalize per-row denom (reduce per-lane partials across g)
  lrun += __shfl_xor(lrun, 16, 64);
  lrun += __shfl_xor(lrun, 32, 64);
  float linv = 1.0f / lrun;
#pragma unroll
  for (int r = 0; r < 4; ++r) {
    float inv = __shfl(linv, 20 * g + r, 64);
    int t = q0 + wave * 16 + g * 4 + r;
#pragma unroll
    for (int n = 0; n < 4; ++n) {
      int e = h * 64 + n * 16 + qid;
      AO[((size_t)b * 2048 + t) * 1024 + e] = f2bf(oacc[n][r] * inv);
    }
  }
#undef STAGE
#undef LOADMASK
#undef COMPUTE
}

// ---------------- launch ----------------
extern "C" void kernel_launch(void* const* d_in, const int* in_sizes, int n_in,
                              void* d_out, int out_size, void* d_ws, size_t ws_size,
                              hipStream_t stream) {
  const float* x     = (const float*)d_in[0];
  const float* mask  = (const float*)d_in[1];
  const float* w_in  = (const float*)d_in[2];
  const float* b_in  = (const float*)d_in[3];
  const float* w_out = (const float*)d_in[4];
  const float* b_out = (const float*)d_in[5];
  float* out = (float*)d_out;

  u16* xbf  = (u16*)d_ws;
  u16* wbf  = xbf  + (size_t)8192 * 1024;
  u16* owbf = wbf  + (size_t)3072 * 1024;
  u16* qkvp = owbf + (size_t)1024 * 1024;
  u16* vt   = qkvp + (size_t)3 * 8192 * 1024;
  u16* ao   = vt   + (size_t)8192 * 1024;
  float* mws = (float*)(ao + (size_t)8192 * 1024);

  cvt_bf16<<<4096, 256, 0, stream>>>(x, xbf, 8388608);
  cvt_bf16<<<1536, 256, 0, stream>>>(w_in, wbf, 3145728);
  cvt_bf16<<<512, 256, 0, stream>>>(w_out, owbf, 1048576);
  scale_mask<<<32, 256, 0, stream>>>(mask, mws, 8192);

  gemm_bt<<<dim3(24, 64), 256, 0, stream>>>(xbf, wbf, b_in, nullptr, qkvp,
                                            8192, 3072, 1024, 1);
  transv<<<dim3(32, 64), 256, 0, stream>>>(qkvp + (size_t)2 * 8192 * 1024, vt);
  attn_fwd<<<dim3(32, 64), 256, 0, stream>>>(qkvp, qkvp + (size_t)8192 * 1024,
                                             vt, mws, ao);
  gemm_bt<<<dim3(8, 64), 256, 0, stream>>>(ao, owbf, b_out, out, nullptr,
                                           8192, 1024, 1024, 0);
}

// Round 5
// 241.690 us; speedup vs baseline: 1.3275x; 1.0001x over previous
//
#include <hip/hip_runtime.h>
#include <hip/hip_bf16.h>
#include <cstdint>

typedef unsigned short u16;
typedef unsigned int   u32;
typedef __bf16  bf16x8 __attribute__((ext_vector_type(8)));
typedef __bf16  bf16x2 __attribute__((ext_vector_type(2)));
typedef float   f32x4  __attribute__((ext_vector_type(4)));
typedef unsigned short u16x8 __attribute__((ext_vector_type(8)));
typedef unsigned int   u32x2 __attribute__((ext_vector_type(2)));
typedef unsigned int   u32x4 __attribute__((ext_vector_type(4)));

#define GLB(p) ((__attribute__((address_space(1))) void*)(p))
#define LDSP(p) ((__attribute__((address_space(3))) void*)(p))

__device__ __forceinline__ u16 f2bf(float f) {
  u32 u = __builtin_bit_cast(u32, f);
  u32 r = u + 0x7fffu + ((u >> 16) & 1u);
  return (u16)(r >> 16);
}

// ---------------- f32 -> bf16 convert (8 elems/thread) ----------------
__global__ __launch_bounds__(256) void cvt_bf16(const float* __restrict__ in,
                                                u16* __restrict__ out, int n) {
  int i = (blockIdx.x * 256 + threadIdx.x) * 8;
  if (i >= n) return;
  f32x4 a = *(const f32x4*)(in + i);
  f32x4 b = *(const f32x4*)(in + i + 4);
  u16x8 o;
#pragma unroll
  for (int j = 0; j < 4; ++j) { o[j] = f2bf(a[j]); o[4 + j] = f2bf(b[j]); }
  *(u16x8*)(out + i) = o;
}

// ---------------- mask pre-scale: out = in * log2(e) ----------------
__global__ __launch_bounds__(256) void scale_mask(const float* __restrict__ in,
                                                  float* __restrict__ out, int n) {
  int i = blockIdx.x * 256 + threadIdx.x;
  if (i < n) out[i] = in[i] * 1.4426950408889634f;
}

// ---------------- GEMM C = A * B^T (+bias), bf16 MFMA ----------------
// mode 1: pack qkv [sect][b][h][t][d]; Q section pre-scaled by 1/sqrt(d)*log2e
__global__ __launch_bounds__(256) void gemm_bt(
    const u16* __restrict__ A, const u16* __restrict__ B,
    const float* __restrict__ bias,
    float* __restrict__ Cf, u16* __restrict__ Cq,
    int M, int N, int K, int mode) {
  __shared__ char lds[32768];
  char* ldsA = lds;
  char* ldsB = lds + 16384;
  const int tid  = threadIdx.x;
  const int lane = tid & 63;
  const int wave = tid >> 6;
  const int m0 = blockIdx.y * 128;
  const int n0 = blockIdx.x * 128;
  const int wr = (wave >> 1) * 64;
  const int wc = (wave & 1) * 64;

  const u16* gA[4];
  const u16* gB[4];
#pragma unroll
  for (int it = 0; it < 4; ++it) {
    int c  = it * 256 + tid;
    int r  = c >> 3;
    int ch = (c & 7) ^ (r & 7);
    gA[it] = A + (size_t)(m0 + r) * K + ch * 8;
    gB[it] = B + (size_t)(n0 + r) * K + ch * 8;
  }

  f32x4 acc[4][4] = {};

  const int arow  = wr + (lane & 15);
  const int brow  = wc + (lane & 15);
  const int kswz  = (lane & 7) << 4;
  const int kbyte = (lane >> 4) * 16;

  for (int kk = 0; kk < K; kk += 64) {
    __syncthreads();
#pragma unroll
    for (int it = 0; it < 4; ++it) {
      int c = it * 256 + tid;
      __builtin_amdgcn_global_load_lds(GLB(gA[it] + kk), LDSP(ldsA + c * 16), 16, 0, 0);
      __builtin_amdgcn_global_load_lds(GLB(gB[it] + kk), LDSP(ldsB + c * 16), 16, 0, 0);
    }
    __syncthreads();
#pragma unroll
    for (int s = 0; s < 2; ++s) {
      bf16x8 af[4], bfr[4];
#pragma unroll
      for (int i = 0; i < 4; ++i)
        af[i] = *(const bf16x8*)(ldsA + (arow + i * 16) * 128 + ((kbyte + s * 64) ^ kswz));
#pragma unroll
      for (int j = 0; j < 4; ++j)
        bfr[j] = *(const bf16x8*)(ldsB + (brow + j * 16) * 128 + ((kbyte + s * 64) ^ kswz));
#pragma unroll
      for (int i = 0; i < 4; ++i)
#pragma unroll
        for (int j = 0; j < 4; ++j)
          acc[i][j] = __builtin_amdgcn_mfma_f32_16x16x32_bf16(af[i], bfr[j], acc[i][j], 0, 0, 0);
    }
  }

  const int r0 = m0 + wr + (lane >> 4) * 4;
  const int c0 = n0 + wc + (lane & 15);
#pragma unroll
  for (int i = 0; i < 4; ++i) {
#pragma unroll
    for (int j = 0; j < 4; ++j) {
      int col  = c0 + j * 16;
      float bv = bias[col];
#pragma unroll
      for (int r = 0; r < 4; ++r) {
        int row = r0 + i * 16 + r;
        float v = acc[i][j][r] + bv;
        if (mode == 0) {
          Cf[(size_t)row * N + col] = v;
        } else {
          if (col < 1024) v *= 0.18033688011112042f;  // Q pre-scale: log2e/sqrt(64)
          int sect = col >> 10, rem = col & 1023;
          int hh = rem >> 6, dd = rem & 63;
          int bb = row >> 11, tt = row & 2047;
          Cq[((((size_t)sect * 4 + bb) * 16 + hh) * 2048 + tt) * 64 + dd] = f2bf(v);
        }
      }
    }
  }
}

// ---------------- V transpose: [bh][t][d] -> [bh][d][t] ----------------
__global__ __launch_bounds__(256) void transv(const u16* __restrict__ Vp,
                                              u16* __restrict__ Vt) {
  __shared__ u16 tl[64][68];
  const int tid = threadIdx.x;
  const int bh  = blockIdx.y;
  const int t0  = blockIdx.x * 64;
  const u16* src = Vp + ((size_t)bh * 2048 + t0) * 64;
#pragma unroll
  for (int it = 0; it < 2; ++it) {
    int c = it * 256 + tid;
    int r = c >> 3, ch = c & 7;
    u16x8 v = *(const u16x8*)(src + r * 64 + ch * 8);
#pragma unroll
    for (int j = 0; j < 8; ++j) tl[r][ch * 8 + j] = v[j];
  }
  __syncthreads();
  u16* dst = Vt + (size_t)bh * 64 * 2048 + t0;
#pragma unroll
  for (int it = 0; it < 2; ++it) {
    int c = it * 256 + tid;
    int d = c >> 3, ch = c & 7;
    u16x8 v;
#pragma unroll
    for (int j = 0; j < 8; ++j) v[j] = tl[ch * 8 + j][d];
    *(u16x8*)(dst + (size_t)d * 2048 + ch * 8) = v;
  }
}

// ---------------- flash attention fwd ----------------
// Qp: [bh][t][64] bf16 PRE-SCALED by log2e/8; Kp: [bh][t][64]; Vt: [bh][64][t]
// maskS: [b][T] f32 pre-scaled by log2e. AO: [b*T][1024] bf16
// LDS: K0 @0, K1 @8192, V0 @16384, V1 @24576, P @32768 (4 waves x 2KB)
__global__ __launch_bounds__(256, 4) void attn_fwd(
    const u16* __restrict__ Qp, const u16* __restrict__ Kp,
    const u16* __restrict__ Vt, const float* __restrict__ maskS,
    u16* __restrict__ AO) {
  __shared__ char lds[40960];
  const int tid  = threadIdx.x;
  const int lane = tid & 63;
  const int wave = tid >> 6;
  const int g    = lane >> 4;
  const int qid  = lane & 15;
  const int bh = blockIdx.y;
  const int b  = bh >> 4;
  const int h  = bh & 15;
  const int q0 = blockIdx.x * 64;

  const u16* Qbase = Qp + ((size_t)bh * 2048 + q0) * 64;
  const u16* Kbase = Kp + (size_t)bh * 2048 * 64;
  const u16* Vbase = Vt + (size_t)bh * 64 * 2048;
  const float* mrowS = maskS + (size_t)b * 2048;

  // staging sources (pre-swizzled: physical chunk c holds logical (c&7)^(r&7))
  const u16* gK[2];
  const u16* gV[2];
  int ldso[2];
#pragma unroll
  for (int it = 0; it < 2; ++it) {
    int c = it * 256 + tid;
    int r = c >> 3;
    int ch = (c & 7) ^ (r & 7);
    gK[it] = Kbase + (size_t)r * 64 + ch * 8;
    gV[it] = Vbase + (size_t)r * 2048 + ch * 8;
    ldso[it] = c * 16;
  }

#define STAGE(SEL, KVV)                                                        \
  do {                                                                         \
    _Pragma("unroll") for (int it = 0; it < 2; ++it) {                         \
      __builtin_amdgcn_global_load_lds(GLB(gK[it] + (size_t)(KVV) * 64),       \
                                       LDSP(lds + (SEL) * 8192 + ldso[it]), 16, 0, 0); \
      __builtin_amdgcn_global_load_lds(GLB(gV[it] + (KVV)),                    \
                                       LDSP(lds + 16384 + (SEL) * 8192 + ldso[it]), 16, 0, 0); \
    }                                                                          \
  } while (0)

#define LOADMASK(DST, KVV)                                                     \
  do {                                                                         \
    _Pragma("unroll") for (int j = 0; j < 4; ++j)                              \
      DST[j] = *(const f32x4*)(mrowS + (KVV) + j * 16 + g * 4);                \
  } while (0)

  // Q fragments straight from global (pre-scaled at GEMM epilogue)
  bf16x8 qa[2];
  {
    int qrow = wave * 16 + qid;
#pragma unroll
    for (int s = 0; s < 2; ++s)
      qa[s] = __builtin_bit_cast(bf16x8, *(const u16x8*)(Qbase + qrow * 64 + 8 * g + 32 * s));
  }

  // constant ones B-fragment (for row-sum via MFMA)
  bf16x8 onesb;
  {
    u16x8 ob;
#pragma unroll
    for (int i = 0; i < 8; ++i) ob[i] = 0x3F80;
    onesb = __builtin_bit_cast(bf16x8, ob);
  }

  f32x4 oacc[4] = {};
  f32x4 lsum = {};       // row-sum accumulator, same C-layout rows as oacc
  float mrun = -1e30f;   // running max (log2 domain) for q-row = qid

  // hoisted XOR-swizzled LDS read bases (all K/V reads = base + const offset)
  const int xoff = (g * 16) ^ ((qid & 7) << 4);
  const char* kb0 = lds + qid * 128 + xoff;          // s = 0
  const char* kb1 = lds + qid * 128 + (xoff ^ 64);   // s = 1

  // P-buffer addressing (conflict-free slot swizzle), hoisted pointers
  const int q0b = qid & 1, q1b = (qid >> 1) & 1, q2b = (qid >> 2) & 1, q3b = qid >> 3;
  const int g0 = g & 1, g1 = g >> 1;
  const int pbase = 32768 + wave * 2048 + qid * 128;
  const int ws0  = (q3b ^ g0) | ((q0b ^ g1) << 1) | (q1b << 2) | (q2b << 3);
  const int slo0 = q3b | ((q0b ^ g0) << 1) | ((q1b ^ g1) << 2) | (q2b << 3);
  char* pwp[4];
  const char* prp[4];
#pragma unroll
  for (int j = 0; j < 4; ++j) pwp[j] = lds + pbase + (ws0 ^ (j << 2)) * 8;
#pragma unroll
  for (int s = 0; s < 2; ++s) {
    prp[2 * s]     = lds + pbase + ((slo0 ^ (s << 3))) * 8;
    prp[2 * s + 1] = lds + pbase + ((slo0 ^ (s << 3)) ^ 1) * 8;
  }

#define COMPUTE(SEL, MK)                                                       \
  do {                                                                         \
    f32x4 sv[4];                                                               \
    _Pragma("unroll") for (int j = 0; j < 4; ++j) {                            \
      bf16x8 k0 = *(const bf16x8*)(kb0 + (SEL) * 8192 + j * 2048);             \
      sv[j] = __builtin_amdgcn_mfma_f32_16x16x32_bf16(k0, qa[0], MK[j], 0, 0, 0); \
      bf16x8 k1 = *(const bf16x8*)(kb1 + (SEL) * 8192 + j * 2048);             \
      sv[j] = __builtin_amdgcn_mfma_f32_16x16x32_bf16(k1, qa[1], sv[j], 0, 0, 0); \
    }                                                                          \
    float pm;                                                                  \
    {                                                                          \
      f32x4 m4;                                                                \
      _Pragma("unroll") for (int r = 0; r < 4; ++r)                            \
        m4[r] = fmaxf(fmaxf(sv[0][r], sv[1][r]), fmaxf(sv[2][r], sv[3][r]));   \
      pm = fmaxf(fmaxf(m4[0], m4[1]), fmaxf(m4[2], m4[3]));                    \
    }                                                                          \
    if (!__all(pm <= mrun + 8.f)) {                                            \
      pm = fmaxf(pm, __shfl_xor(pm, 16, 64));                                  \
      pm = fmaxf(pm, __shfl_xor(pm, 32, 64));                                  \
      float mnew = fmaxf(mrun, pm);                                            \
      float sc = exp2f(mrun - mnew);                                           \
      mrun = mnew;                                                             \
      _Pragma("unroll") for (int r = 0; r < 4; ++r) {                          \
        float scr = __shfl(sc, 20 * g + r, 64);                                \
        lsum[r] *= scr;                                                        \
        _Pragma("unroll") for (int n = 0; n < 4; ++n) oacc[n][r] *= scr;       \
      }                                                                        \
    }                                                                          \
    _Pragma("unroll") for (int j = 0; j < 4; ++j)                              \
      _Pragma("unroll") for (int r = 0; r < 4; ++r)                            \
        sv[j][r] = exp2f(sv[j][r] - mrun);                                     \
    _Pragma("unroll") for (int j = 0; j < 4; ++j) {                            \
      bf16x2 lo = {(__bf16)sv[j][0], (__bf16)sv[j][1]};                        \
      bf16x2 hi = {(__bf16)sv[j][2], (__bf16)sv[j][3]};                        \
      u32x2 w;                                                                 \
      w[0] = __builtin_bit_cast(u32, lo);                                      \
      w[1] = __builtin_bit_cast(u32, hi);                                      \
      *(u32x2*)(pwp[j]) = w;                                                   \
    }                                                                          \
    bf16x8 pa[2];                                                              \
    _Pragma("unroll") for (int s = 0; s < 2; ++s) {                            \
      u32x2 lo = *(const u32x2*)(prp[2 * s]);                                  \
      u32x2 hi = *(const u32x2*)(prp[2 * s + 1]);                              \
      u32x4 pw;                                                                \
      pw[0] = lo[0]; pw[1] = lo[1]; pw[2] = hi[0]; pw[3] = hi[1];              \
      pa[s] = __builtin_bit_cast(bf16x8, pw);                                  \
    }                                                                          \
    lsum = __builtin_amdgcn_mfma_f32_16x16x32_bf16(pa[0], onesb, lsum, 0, 0, 0); \
    lsum = __builtin_amdgcn_mfma_f32_16x16x32_bf16(pa[1], onesb, lsum, 0, 0, 0); \
    _Pragma("unroll") for (int n = 0; n < 4; ++n) {                            \
      bf16x8 v0 = *(const bf16x8*)(kb0 + 16384 + (SEL) * 8192 + n * 2048);     \
      oacc[n] = __builtin_amdgcn_mfma_f32_16x16x32_bf16(pa[0], v0, oacc[n], 0, 0, 0); \
      bf16x8 v1 = *(const bf16x8*)(kb1 + 16384 + (SEL) * 8192 + n * 2048);     \
      oacc[n] = __builtin_amdgcn_mfma_f32_16x16x32_bf16(pa[1], v1, oacc[n], 0, 0, 0); \
    }                                                                          \
  } while (0)

  f32x4 m0[4], m1[4];
  STAGE(0, 0);
  LOADMASK(m0, 0);
  __syncthreads();

  for (int kv = 0; kv < 2048; kv += 128) {
    if (kv + 64 < 2048) { STAGE(1, kv + 64); LOADMASK(m1, kv + 64); }
    COMPUTE(0, m0);
    __syncthreads();
    if (kv + 128 < 2048) { STAGE(0, kv + 128); LOADMASK(m0, kv + 128); }
    COMPUTE(1, m1);
    __syncthreads();
  }

  // epilogue: denom is row-aligned with oacc — no cross-lane reduce needed
#pragma unroll
  for (int r = 0; r < 4; ++r) {
    float inv = 1.0f / lsum[r];
    int t = q0 + wave * 16 + g * 4 + r;
#pragma unroll
    for (int n = 0; n < 4; ++n) {
      int e = h * 64 + n * 16 + qid;
      AO[((size_t)b * 2048 + t) * 1024 + e] = f2bf(oacc[n][r] * inv);
    }
  }
#undef STAGE
#undef LOADMASK
#undef COMPUTE
}

// ---------------- launch ----------------
extern "C" void kernel_launch(void* const* d_in, const int* in_sizes, int n_in,
                              void* d_out, int out_size, void* d_ws, size_t ws_size,
                              hipStream_t stream) {
  const float* x     = (const float*)d_in[0];
  const float* mask  = (const float*)d_in[1];
  const float* w_in  = (const float*)d_in[2];
  const float* b_in  = (const float*)d_in[3];
  const float* w_out = (const float*)d_in[4];
  const float* b_out = (const float*)d_in[5];
  float* out = (float*)d_out;

  u16* xbf  = (u16*)d_ws;
  u16* wbf  = xbf  + (size_t)8192 * 1024;
  u16* owbf = wbf  + (size_t)3072 * 1024;
  u16* qkvp = owbf + (size_t)1024 * 1024;
  u16* vt   = qkvp + (size_t)3 * 8192 * 1024;
  u16* ao   = vt   + (size_t)8192 * 1024;
  float* mws = (float*)(ao + (size_t)8192 * 1024);

  cvt_bf16<<<4096, 256, 0, stream>>>(x, xbf, 8388608);
  cvt_bf16<<<1536, 256, 0, stream>>>(w_in, wbf, 3145728);
  cvt_bf16<<<512, 256, 0, stream>>>(w_out, owbf, 1048576);
  scale_mask<<<32, 256, 0, stream>>>(mask, mws, 8192);

  gemm_bt<<<dim3(24, 64), 256, 0, stream>>>(xbf, wbf, b_in, nullptr, qkvp,
                                            8192, 3072, 1024, 1);
  transv<<<dim3(32, 64), 256, 0, stream>>>(qkvp + (size_t)2 * 8192 * 1024, vt);
  attn_fwd<<<dim3(32, 64), 256, 0, stream>>>(qkvp, qkvp + (size_t)8192 * 1024,
                                             vt, mws, ao);
  gemm_bt<<<dim3(8, 64), 256, 0, stream>>>(ao, owbf, b_out, out, nullptr,
                                           8192, 1024, 1024, 0);
}

// Round 6
// 240.471 us; speedup vs baseline: 1.3343x; 1.0051x over previous
//
#include <hip/hip_runtime.h>
#include <hip/hip_bf16.h>
#include <cstdint>

typedef unsigned short u16;
typedef unsigned int   u32;
typedef __bf16  bf16x8 __attribute__((ext_vector_type(8)));
typedef __bf16  bf16x2 __attribute__((ext_vector_type(2)));
typedef float   f32x4  __attribute__((ext_vector_type(4)));
typedef float   f32x16 __attribute__((ext_vector_type(16)));
typedef unsigned short u16x8 __attribute__((ext_vector_type(8)));
typedef unsigned int   u32x2 __attribute__((ext_vector_type(2)));
typedef unsigned int   u32x4 __attribute__((ext_vector_type(4)));

#define GLB(p) ((__attribute__((address_space(1))) void*)(p))
#define LDSP(p) ((__attribute__((address_space(3))) void*)(p))

__device__ __forceinline__ u16 f2bf(float f) {
  u32 u = __builtin_bit_cast(u32, f);
  u32 r = u + 0x7fffu + ((u >> 16) & 1u);
  return (u16)(r >> 16);
}

// ---------------- f32 -> bf16 convert (8 elems/thread) ----------------
__global__ __launch_bounds__(256) void cvt_bf16(const float* __restrict__ in,
                                                u16* __restrict__ out, int n) {
  int i = (blockIdx.x * 256 + threadIdx.x) * 8;
  if (i >= n) return;
  f32x4 a = *(const f32x4*)(in + i);
  f32x4 b = *(const f32x4*)(in + i + 4);
  u16x8 o;
#pragma unroll
  for (int j = 0; j < 4; ++j) { o[j] = f2bf(a[j]); o[4 + j] = f2bf(b[j]); }
  *(u16x8*)(out + i) = o;
}

// ---------------- mask pre-scale: out = in * log2(e) ----------------
__global__ __launch_bounds__(256) void scale_mask(const float* __restrict__ in,
                                                  float* __restrict__ out, int n) {
  int i = blockIdx.x * 256 + threadIdx.x;
  if (i < n) out[i] = in[i] * 1.4426950408889634f;
}

// ---------------- GEMM C = A * B^T (+bias), bf16 MFMA ----------------
// mode 1: pack qkv [sect][b][h][t][d]; Q section pre-scaled by 1/sqrt(d)*log2e
__global__ __launch_bounds__(256) void gemm_bt(
    const u16* __restrict__ A, const u16* __restrict__ B,
    const float* __restrict__ bias,
    float* __restrict__ Cf, u16* __restrict__ Cq,
    int M, int N, int K, int mode) {
  __shared__ char lds[32768];
  char* ldsA = lds;
  char* ldsB = lds + 16384;
  const int tid  = threadIdx.x;
  const int lane = tid & 63;
  const int wave = tid >> 6;
  const int m0 = blockIdx.y * 128;
  const int n0 = blockIdx.x * 128;
  const int wr = (wave >> 1) * 64;
  const int wc = (wave & 1) * 64;

  const u16* gA[4];
  const u16* gB[4];
#pragma unroll
  for (int it = 0; it < 4; ++it) {
    int c  = it * 256 + tid;
    int r  = c >> 3;
    int ch = (c & 7) ^ (r & 7);
    gA[it] = A + (size_t)(m0 + r) * K + ch * 8;
    gB[it] = B + (size_t)(n0 + r) * K + ch * 8;
  }

  f32x4 acc[4][4] = {};

  const int arow  = wr + (lane & 15);
  const int brow  = wc + (lane & 15);
  const int kswz  = (lane & 7) << 4;
  const int kbyte = (lane >> 4) * 16;

  for (int kk = 0; kk < K; kk += 64) {
    __syncthreads();
#pragma unroll
    for (int it = 0; it < 4; ++it) {
      int c = it * 256 + tid;
      __builtin_amdgcn_global_load_lds(GLB(gA[it] + kk), LDSP(ldsA + c * 16), 16, 0, 0);
      __builtin_amdgcn_global_load_lds(GLB(gB[it] + kk), LDSP(ldsB + c * 16), 16, 0, 0);
    }
    __syncthreads();
#pragma unroll
    for (int s = 0; s < 2; ++s) {
      bf16x8 af[4], bfr[4];
#pragma unroll
      for (int i = 0; i < 4; ++i)
        af[i] = *(const bf16x8*)(ldsA + (arow + i * 16) * 128 + ((kbyte + s * 64) ^ kswz));
#pragma unroll
      for (int j = 0; j < 4; ++j)
        bfr[j] = *(const bf16x8*)(ldsB + (brow + j * 16) * 128 + ((kbyte + s * 64) ^ kswz));
#pragma unroll
      for (int i = 0; i < 4; ++i)
#pragma unroll
        for (int j = 0; j < 4; ++j)
          acc[i][j] = __builtin_amdgcn_mfma_f32_16x16x32_bf16(af[i], bfr[j], acc[i][j], 0, 0, 0);
    }
  }

  const int r0 = m0 + wr + (lane >> 4) * 4;
  const int c0 = n0 + wc + (lane & 15);
#pragma unroll
  for (int i = 0; i < 4; ++i) {
#pragma unroll
    for (int j = 0; j < 4; ++j) {
      int col  = c0 + j * 16;
      float bv = bias[col];
#pragma unroll
      for (int r = 0; r < 4; ++r) {
        int row = r0 + i * 16 + r;
        float v = acc[i][j][r] + bv;
        if (mode == 0) {
          Cf[(size_t)row * N + col] = v;
        } else {
          if (col < 1024) v *= 0.18033688011112042f;  // Q pre-scale: log2e/sqrt(64)
          int sect = col >> 10, rem = col & 1023;
          int hh = rem >> 6, dd = rem & 63;
          int bb = row >> 11, tt = row & 2047;
          Cq[((((size_t)sect * 4 + bb) * 16 + hh) * 2048 + tt) * 64 + dd] = f2bf(v);
        }
      }
    }
  }
}

// ---------------- V transpose: [bh][t][d] -> [bh][d][t] ----------------
__global__ __launch_bounds__(256) void transv(const u16* __restrict__ Vp,
                                              u16* __restrict__ Vt) {
  __shared__ u16 tl[64][68];
  const int tid = threadIdx.x;
  const int bh  = blockIdx.y;
  const int t0  = blockIdx.x * 64;
  const u16* src = Vp + ((size_t)bh * 2048 + t0) * 64;
#pragma unroll
  for (int it = 0; it < 2; ++it) {
    int c = it * 256 + tid;
    int r = c >> 3, ch = c & 7;
    u16x8 v = *(const u16x8*)(src + r * 64 + ch * 8);
#pragma unroll
    for (int j = 0; j < 8; ++j) tl[r][ch * 8 + j] = v[j];
  }
  __syncthreads();
  u16* dst = Vt + (size_t)bh * 64 * 2048 + t0;
#pragma unroll
  for (int it = 0; it < 2; ++it) {
    int c = it * 256 + tid;
    int d = c >> 3, ch = c & 7;
    u16x8 v;
#pragma unroll
    for (int j = 0; j < 8; ++j) v[j] = tl[ch * 8 + j][d];
    *(u16x8*)(dst + (size_t)d * 2048 + ch * 8) = v;
  }
}

// ---------------- flash attention fwd, 32x32 MFMA, QBLK=128 ----------------
// Qp: [bh][t][64] bf16 PRE-SCALED by log2e/8; Kp: [bh][t][64]; Vt: [bh][64][t]
// maskS: [b][T] f32 pre-scaled by log2e. AO: [b*T][1024] bf16
// LDS: K dbuf @0 (2x8K), V dbuf @16384 (2x8K), mask row @32768 (8K)
__global__ __launch_bounds__(256, 3) void attn_fwd(
    const u16* __restrict__ Qp, const u16* __restrict__ Kp,
    const u16* __restrict__ Vt, const float* __restrict__ maskS,
    u16* __restrict__ AO) {
  __shared__ char lds[40960];
  const int tid  = threadIdx.x;
  const int lane = tid & 63;
  const int wave = tid >> 6;
  const int lam  = lane & 31;       // q-col within wave's 32 rows
  const int b5   = lane >> 5;       // k-half selector

  // XCD-aware swizzle: dispatch slot s -> work w so each XCD owns 8 heads
  const int s  = blockIdx.x;
  const int w  = (s & 7) * 128 + (s >> 3);
  const int qt = w & 15;
  const int bh = w >> 4;
  const int b  = bh >> 4;
  const int h  = bh & 15;
  const int q0 = qt * 128;

  const u16* Qbase = Qp + ((size_t)bh * 2048 + q0) * 64;
  const u16* Kbase = Kp + (size_t)bh * 2048 * 64;
  const u16* Vbase = Vt + (size_t)bh * 64 * 2048;
  const float* mrowS = maskS + (size_t)b * 2048;

  // staging sources (pre-swizzled: physical granule c&7 holds logical (c&7)^(r&7))
  const u16* gK[2];
  const u16* gV[2];
  int ldso[2];
#pragma unroll
  for (int it = 0; it < 2; ++it) {
    int c = it * 256 + tid;
    int r = c >> 3;
    int ch = (c & 7) ^ (r & 7);
    gK[it] = Kbase + (size_t)r * 64 + ch * 8;
    gV[it] = Vbase + (size_t)r * 2048 + ch * 8;
    ldso[it] = c * 16;
  }

#define STAGE(SEL, KVV)                                                        \
  do {                                                                         \
    _Pragma("unroll") for (int it = 0; it < 2; ++it) {                         \
      __builtin_amdgcn_global_load_lds(GLB(gK[it] + (size_t)(KVV) * 64),       \
                                       LDSP(lds + (SEL) * 8192 + ldso[it]), 16, 0, 0); \
      __builtin_amdgcn_global_load_lds(GLB(gV[it] + (KVV)),                    \
                                       LDSP(lds + 16384 + (SEL) * 8192 + ldso[it]), 16, 0, 0); \
    }                                                                          \
  } while (0)

  // Q fragments from global: qb[kb] = Q[qrow][kb*16 + b5*8 .. +7]
  bf16x8 qb[4];
  {
    int qrow = wave * 32 + lam;
#pragma unroll
    for (int kb = 0; kb < 4; ++kb)
      qb[kb] = __builtin_bit_cast(bf16x8,
               *(const u16x8*)(Qbase + qrow * 64 + kb * 16 + b5 * 8));
  }

  f32x16 oacc0 = {}, oacc1 = {};
  float mrun = -1e30f;
  float lrun = 0.f;

  // per-lane constant LDS read geometry: granule gg[j] for K(kb=j) / V(chunk=j)
  int gg[4];
#pragma unroll
  for (int j = 0; j < 4; ++j) gg[j] = (((j << 1) | b5) ^ (lam & 7)) << 4;
  const char* rowb = lds + lam * 128;   // + SEL*8192 + c*4096 + gg[]

#define COMPUTE32(SEL, KVV)                                                    \
  do {                                                                         \
    f32x16 sv0, sv1;                                                           \
    _Pragma("unroll") for (int q2 = 0; q2 < 4; ++q2) {                         \
      f32x4 mk0 = *(const f32x4*)(lds + 32768 + ((KVV) + 8 * q2 + 4 * b5) * 4);\
      f32x4 mk1 = *(const f32x4*)(lds + 32768 + ((KVV) + 32 + 8 * q2 + 4 * b5) * 4);\
      _Pragma("unroll") for (int i = 0; i < 4; ++i) {                          \
        sv0[q2 * 4 + i] = mk0[i];                                              \
        sv1[q2 * 4 + i] = mk1[i];                                              \
      }                                                                        \
    }                                                                          \
    _Pragma("unroll") for (int kb = 0; kb < 4; ++kb) {                         \
      bf16x8 kf0 = *(const bf16x8*)(rowb + (SEL) * 8192 + gg[kb]);             \
      sv0 = __builtin_amdgcn_mfma_f32_32x32x16_bf16(kf0, qb[kb], sv0, 0, 0, 0);\
      bf16x8 kf1 = *(const bf16x8*)(rowb + (SEL) * 8192 + 4096 + gg[kb]);      \
      sv1 = __builtin_amdgcn_mfma_f32_32x32x16_bf16(kf1, qb[kb], sv1, 0, 0, 0);\
    }                                                                          \
    float pm;                                                                  \
    {                                                                          \
      float a0 = fmaxf(sv0[0], sv0[1]), a1 = fmaxf(sv0[2], sv0[3]);            \
      _Pragma("unroll") for (int i = 4; i < 16; i += 4) {                      \
        a0 = fmaxf(a0, fmaxf(sv0[i], sv0[i + 1]));                             \
        a1 = fmaxf(a1, fmaxf(sv0[i + 2], sv0[i + 3]));                         \
      }                                                                        \
      _Pragma("unroll") for (int i = 0; i < 16; i += 4) {                      \
        a0 = fmaxf(a0, fmaxf(sv1[i], sv1[i + 1]));                             \
        a1 = fmaxf(a1, fmaxf(sv1[i + 2], sv1[i + 3]));                         \
      }                                                                        \
      pm = fmaxf(a0, a1);                                                      \
      pm = fmaxf(pm, __shfl_xor(pm, 32, 64));                                  \
    }                                                                          \
    if (!__all(pm <= mrun + 8.f)) {                                            \
      float mnew = fmaxf(mrun, pm);                                            \
      float sc = exp2f(mrun - mnew);                                           \
      mrun = mnew;                                                             \
      lrun *= sc;                                                              \
      _Pragma("unroll") for (int i = 0; i < 16; ++i) {                         \
        oacc0[i] *= sc;                                                        \
        oacc1[i] *= sc;                                                        \
      }                                                                        \
    }                                                                          \
    float rs = 0.f;                                                            \
    _Pragma("unroll") for (int i = 0; i < 16; ++i) {                           \
      sv0[i] = exp2f(sv0[i] - mrun);                                           \
      sv1[i] = exp2f(sv1[i] - mrun);                                           \
      rs += sv0[i] + sv1[i];                                                   \
    }                                                                          \
    lrun += rs;                                                                \
    bf16x8 pa[4];                                                              \
    _Pragma("unroll") for (int c = 0; c < 2; ++c) {                            \
      u32 wv[8], pw[8];                                                        \
      _Pragma("unroll") for (int i = 0; i < 8; ++i) {                          \
        float e0 = (c == 0) ? sv0[2 * i] : sv1[2 * i];                         \
        float e1 = (c == 0) ? sv0[2 * i + 1] : sv1[2 * i + 1];                 \
        bf16x2 t = {(__bf16)e0, (__bf16)e1};                                   \
        wv[i] = __builtin_bit_cast(u32, t);                                    \
      }                                                                        \
      _Pragma("unroll") for (int i = 0; i < 8; ++i)                            \
        pw[i] = __shfl_xor(wv[i], 32, 64);                                     \
      _Pragma("unroll") for (int kb = 0; kb < 2; ++kb) {                       \
        int o = kb * 4;                                                        \
        u32x4 pk;                                                              \
        pk[0] = b5 ? pw[o + 2] : wv[o + 0];                                    \
        pk[1] = b5 ? pw[o + 3] : wv[o + 1];                                    \
        pk[2] = b5 ? wv[o + 2] : pw[o + 0];                                    \
        pk[3] = b5 ? wv[o + 3] : pw[o + 1];                                    \
        pa[c * 2 + kb] = __builtin_bit_cast(bf16x8, pk);                       \
      }                                                                        \
    }                                                                          \
    _Pragma("unroll") for (int j = 0; j < 4; ++j) {                            \
      bf16x8 vf0 = *(const bf16x8*)(rowb + 16384 + (SEL) * 8192 + gg[j]);      \
      oacc0 = __builtin_amdgcn_mfma_f32_32x32x16_bf16(vf0, pa[j], oacc0, 0, 0, 0); \
      bf16x8 vf1 = *(const bf16x8*)(rowb + 16384 + (SEL) * 8192 + 4096 + gg[j]); \
      oacc1 = __builtin_amdgcn_mfma_f32_32x32x16_bf16(vf1, pa[j], oacc1, 0, 0, 0); \
    }                                                                          \
  } while (0)

  // prologue: stage tile 0 + mask row
  STAGE(0, 0);
#pragma unroll
  for (int it = 0; it < 2; ++it) {
    int c = it * 256 + tid;
    __builtin_amdgcn_global_load_lds(GLB(mrowS + c * 4), LDSP(lds + 32768 + c * 16), 16, 0, 0);
  }
  __syncthreads();

  for (int kv = 0; kv < 2048; kv += 128) {
    if (kv + 64 < 2048) STAGE(1, kv + 64);
    COMPUTE32(0, kv);
    __syncthreads();
    if (kv + 128 < 2048) STAGE(0, kv + 128);
    COMPUTE32(1, kv + 64);
    __syncthreads();
  }

  // epilogue: combine partner halves of the denominator, write O
  float ltot = lrun + __shfl_xor(lrun, 32, 64);
  float linv = 1.0f / ltot;
  int t = q0 + wave * 32 + lam;
  u16* aorow = AO + ((size_t)b * 2048 + t) * 1024 + h * 64;
#pragma unroll
  for (int n = 0; n < 2; ++n) {
#pragma unroll
    for (int q2 = 0; q2 < 4; ++q2) {
      const f32x16& oc = n ? oacc1 : oacc0;
      bf16x2 lo = {(__bf16)(oc[q2 * 4 + 0] * linv), (__bf16)(oc[q2 * 4 + 1] * linv)};
      bf16x2 hi = {(__bf16)(oc[q2 * 4 + 2] * linv), (__bf16)(oc[q2 * 4 + 3] * linv)};
      u32x2 wv;
      wv[0] = __builtin_bit_cast(u32, lo);
      wv[1] = __builtin_bit_cast(u32, hi);
      int d0 = 32 * n + 8 * q2 + 4 * b5;
      *(u32x2*)(aorow + d0) = wv;
    }
  }
#undef STAGE
#undef COMPUTE32
}

// ---------------- launch ----------------
extern "C" void kernel_launch(void* const* d_in, const int* in_sizes, int n_in,
                              void* d_out, int out_size, void* d_ws, size_t ws_size,
                              hipStream_t stream) {
  const float* x     = (const float*)d_in[0];
  const float* mask  = (const float*)d_in[1];
  const float* w_in  = (const float*)d_in[2];
  const float* b_in  = (const float*)d_in[3];
  const float* w_out = (const float*)d_in[4];
  const float* b_out = (const float*)d_in[5];
  float* out = (float*)d_out;

  u16* xbf  = (u16*)d_ws;
  u16* wbf  = xbf  + (size_t)8192 * 1024;
  u16* owbf = wbf  + (size_t)3072 * 1024;
  u16* qkvp = owbf + (size_t)1024 * 1024;
  u16* vt   = qkvp + (size_t)3 * 8192 * 1024;
  u16* ao   = vt   + (size_t)8192 * 1024;
  float* mws = (float*)(ao + (size_t)8192 * 1024);

  cvt_bf16<<<4096, 256, 0, stream>>>(x, xbf, 8388608);
  cvt_bf16<<<1536, 256, 0, stream>>>(w_in, wbf, 3145728);
  cvt_bf16<<<512, 256, 0, stream>>>(w_out, owbf, 1048576);
  scale_mask<<<32, 256, 0, stream>>>(mask, mws, 8192);

  gemm_bt<<<dim3(24, 64), 256, 0, stream>>>(xbf, wbf, b_in, nullptr, qkvp,
                                            8192, 3072, 1024, 1);
  transv<<<dim3(32, 64), 256, 0, stream>>>(qkvp + (size_t)2 * 8192 * 1024, vt);
  attn_fwd<<<1024, 256, 0, stream>>>(qkvp, qkvp + (size_t)8192 * 1024,
                                     vt, mws, ao);
  gemm_bt<<<dim3(8, 64), 256, 0, stream>>>(ao, owbf, b_out, out, nullptr,
                                           8192, 1024, 1024, 0);
}

// Round 7
// 218.722 us; speedup vs baseline: 1.4669x; 1.0994x over previous
//
#include <hip/hip_runtime.h>
#include <hip/hip_bf16.h>
#include <cstdint>

typedef unsigned short u16;
typedef unsigned int   u32;
typedef __bf16  bf16x8 __attribute__((ext_vector_type(8)));
typedef __bf16  bf16x2 __attribute__((ext_vector_type(2)));
typedef float   f32x4  __attribute__((ext_vector_type(4)));
typedef float   f32x16 __attribute__((ext_vector_type(16)));
typedef unsigned short u16x8 __attribute__((ext_vector_type(8)));
typedef unsigned int   u32x2 __attribute__((ext_vector_type(2)));
typedef unsigned int   u32x4 __attribute__((ext_vector_type(4)));

#define GLB(p) ((__attribute__((address_space(1))) void*)(p))
#define LDSP(p) ((__attribute__((address_space(3))) void*)(p))

__device__ __forceinline__ u16 f2bf(float f) {
  u32 u = __builtin_bit_cast(u32, f);
  u32 r = u + 0x7fffu + ((u >> 16) & 1u);
  return (u16)(r >> 16);
}

// ---------------- f32 -> bf16 convert (8 elems/thread) ----------------
__global__ __launch_bounds__(256) void cvt_bf16(const float* __restrict__ in,
                                                u16* __restrict__ out, int n) {
  int i = (blockIdx.x * 256 + threadIdx.x) * 8;
  if (i >= n) return;
  f32x4 a = *(const f32x4*)(in + i);
  f32x4 b = *(const f32x4*)(in + i + 4);
  u16x8 o;
#pragma unroll
  for (int j = 0; j < 4; ++j) { o[j] = f2bf(a[j]); o[4 + j] = f2bf(b[j]); }
  *(u16x8*)(out + i) = o;
}

// -------- mask pre-scale: out = in * log2(e) - 8 (static-max fold) --------
__global__ __launch_bounds__(256) void scale_mask(const float* __restrict__ in,
                                                  float* __restrict__ out, int n) {
  int i = blockIdx.x * 256 + threadIdx.x;
  if (i < n) out[i] = in[i] * 1.4426950408889634f - 8.0f;
}

// ---------------- GEMM C = A * B^T (+bias), bf16 MFMA ----------------
// mode 1: pack qkv [sect][b][h][t][d]; Q section pre-scaled by 1/sqrt(d)*log2e
__global__ __launch_bounds__(256) void gemm_bt(
    const u16* __restrict__ A, const u16* __restrict__ B,
    const float* __restrict__ bias,
    float* __restrict__ Cf, u16* __restrict__ Cq,
    int M, int N, int K, int mode) {
  __shared__ char lds[32768];
  char* ldsA = lds;
  char* ldsB = lds + 16384;
  const int tid  = threadIdx.x;
  const int lane = tid & 63;
  const int wave = tid >> 6;
  const int m0 = blockIdx.y * 128;
  const int n0 = blockIdx.x * 128;
  const int wr = (wave >> 1) * 64;
  const int wc = (wave & 1) * 64;

  const u16* gA[4];
  const u16* gB[4];
#pragma unroll
  for (int it = 0; it < 4; ++it) {
    int c  = it * 256 + tid;
    int r  = c >> 3;
    int ch = (c & 7) ^ (r & 7);
    gA[it] = A + (size_t)(m0 + r) * K + ch * 8;
    gB[it] = B + (size_t)(n0 + r) * K + ch * 8;
  }

  f32x4 acc[4][4] = {};

  const int arow  = wr + (lane & 15);
  const int brow  = wc + (lane & 15);
  const int kswz  = (lane & 7) << 4;
  const int kbyte = (lane >> 4) * 16;

  for (int kk = 0; kk < K; kk += 64) {
    __syncthreads();
#pragma unroll
    for (int it = 0; it < 4; ++it) {
      int c = it * 256 + tid;
      __builtin_amdgcn_global_load_lds(GLB(gA[it] + kk), LDSP(ldsA + c * 16), 16, 0, 0);
      __builtin_amdgcn_global_load_lds(GLB(gB[it] + kk), LDSP(ldsB + c * 16), 16, 0, 0);
    }
    __syncthreads();
#pragma unroll
    for (int s = 0; s < 2; ++s) {
      bf16x8 af[4], bfr[4];
#pragma unroll
      for (int i = 0; i < 4; ++i)
        af[i] = *(const bf16x8*)(ldsA + (arow + i * 16) * 128 + ((kbyte + s * 64) ^ kswz));
#pragma unroll
      for (int j = 0; j < 4; ++j)
        bfr[j] = *(const bf16x8*)(ldsB + (brow + j * 16) * 128 + ((kbyte + s * 64) ^ kswz));
#pragma unroll
      for (int i = 0; i < 4; ++i)
#pragma unroll
        for (int j = 0; j < 4; ++j)
          acc[i][j] = __builtin_amdgcn_mfma_f32_16x16x32_bf16(af[i], bfr[j], acc[i][j], 0, 0, 0);
    }
  }

  const int r0 = m0 + wr + (lane >> 4) * 4;
  const int c0 = n0 + wc + (lane & 15);
#pragma unroll
  for (int i = 0; i < 4; ++i) {
#pragma unroll
    for (int j = 0; j < 4; ++j) {
      int col  = c0 + j * 16;
      float bv = bias[col];
#pragma unroll
      for (int r = 0; r < 4; ++r) {
        int row = r0 + i * 16 + r;
        float v = acc[i][j][r] + bv;
        if (mode == 0) {
          Cf[(size_t)row * N + col] = v;
        } else {
          if (col < 1024) v *= 0.18033688011112042f;  // Q pre-scale: log2e/sqrt(64)
          int sect = col >> 10, rem = col & 1023;
          int hh = rem >> 6, dd = rem & 63;
          int bb = row >> 11, tt = row & 2047;
          Cq[((((size_t)sect * 4 + bb) * 16 + hh) * 2048 + tt) * 64 + dd] = f2bf(v);
        }
      }
    }
  }
}

// ---------------- V transpose: [bh][t][d] -> [bh][d][t] ----------------
__global__ __launch_bounds__(256) void transv(const u16* __restrict__ Vp,
                                              u16* __restrict__ Vt) {
  __shared__ u16 tl[64][68];
  const int tid = threadIdx.x;
  const int bh  = blockIdx.y;
  const int t0  = blockIdx.x * 64;
  const u16* src = Vp + ((size_t)bh * 2048 + t0) * 64;
#pragma unroll
  for (int it = 0; it < 2; ++it) {
    int c = it * 256 + tid;
    int r = c >> 3, ch = c & 7;
    u16x8 v = *(const u16x8*)(src + r * 64 + ch * 8);
#pragma unroll
    for (int j = 0; j < 8; ++j) tl[r][ch * 8 + j] = v[j];
  }
  __syncthreads();
  u16* dst = Vt + (size_t)bh * 64 * 2048 + t0;
#pragma unroll
  for (int it = 0; it < 2; ++it) {
    int c = it * 256 + tid;
    int d = c >> 3, ch = c & 7;
    u16x8 v;
#pragma unroll
    for (int j = 0; j < 8; ++j) v[j] = tl[ch * 8 + j][d];
    *(u16x8*)(dst + (size_t)d * 2048 + ch * 8) = v;
  }
}

// -------- flash attention fwd: 32x32 MFMA, static-max, in-register P --------
// Qp: [bh][t][64] bf16 PRE-SCALED by log2e/8; Kp: [bh][t][64]; Vt: [bh][64][t]
// maskS: [b][T] f32 = mask*log2e - 8 (static max folded in). AO: [b*T][1024] bf16
// LDS: K dbuf @0 (2x8K), V dbuf @16384 (2x8K), mask row @32768 (8K)
__global__ __launch_bounds__(256, 4) void attn_fwd(
    const u16* __restrict__ Qp, const u16* __restrict__ Kp,
    const u16* __restrict__ Vt, const float* __restrict__ maskS,
    u16* __restrict__ AO) {
  __shared__ char lds[40960];
  const int tid  = threadIdx.x;
  const int lane = tid & 63;
  const int wave = tid >> 6;
  const int lam  = lane & 31;       // q-col within wave's 32 rows
  const int b5   = lane >> 5;       // half-wave selector

  // XCD-aware swizzle: each XCD owns 8 heads (K/V L2-resident)
  const int s  = blockIdx.x;
  const int w  = (s & 7) * 128 + (s >> 3);
  const int qt = w & 15;
  const int bh = w >> 4;
  const int b  = bh >> 4;
  const int h  = bh & 15;
  const int q0 = qt * 128;

  const u16* Qbase = Qp + ((size_t)bh * 2048 + q0) * 64;
  const u16* Kbase = Kp + (size_t)bh * 2048 * 64;
  const u16* Vbase = Vt + (size_t)bh * 64 * 2048;
  const float* mrowS = maskS + (size_t)b * 2048;

  // staging sources (pre-swizzled: physical granule c&7 holds logical (c&7)^(r&7))
  const u16* gK[2];
  const u16* gV[2];
  int ldso[2];
#pragma unroll
  for (int it = 0; it < 2; ++it) {
    int c = it * 256 + tid;
    int r = c >> 3;
    int ch = (c & 7) ^ (r & 7);
    gK[it] = Kbase + (size_t)r * 64 + ch * 8;
    gV[it] = Vbase + (size_t)r * 2048 + ch * 8;
    ldso[it] = c * 16;
  }

#define STAGE(SEL, KVV)                                                        \
  do {                                                                         \
    _Pragma("unroll") for (int it = 0; it < 2; ++it) {                         \
      __builtin_amdgcn_global_load_lds(GLB(gK[it] + (size_t)(KVV) * 64),       \
                                       LDSP(lds + (SEL) * 8192 + ldso[it]), 16, 0, 0); \
      __builtin_amdgcn_global_load_lds(GLB(gV[it] + (KVV)),                    \
                                       LDSP(lds + 16384 + (SEL) * 8192 + ldso[it]), 16, 0, 0); \
    }                                                                          \
  } while (0)

  // Q fragments from global: qb[kb] = Q[qrow][kb*16 + b5*8 .. +7]
  bf16x8 qb[4];
  {
    int qrow = wave * 32 + lam;
#pragma unroll
    for (int kb = 0; kb < 4; ++kb)
      qb[kb] = __builtin_bit_cast(bf16x8,
               *(const u16x8*)(Qbase + qrow * 64 + kb * 16 + b5 * 8));
  }

  f32x16 oacc0 = {}, oacc1 = {};
  float lrun = 0.f;   // per-lane partial denominator (static max: no rescale)

  // K-read granules (QK, b128): logical granule (2kb|b5), row = lam
  int gg[4];
#pragma unroll
  for (int j = 0; j < 4; ++j) gg[j] = (((j << 1) | b5) ^ (lam & 7)) << 4;
  // V-read offsets (PV, 2x b64 per chunk): logical granules 2m, 2m+1; +8*b5
  int vga[4], vgb[4];
#pragma unroll
  for (int m = 0; m < 4; ++m) {
    vga[m] = (((m << 1)) ^ (lam & 7)) * 16 + 8 * b5;
    vgb[m] = (((m << 1) | 1) ^ (lam & 7)) * 16 + 8 * b5;
  }
  const char* rowb = lds + lam * 128;

#define COMPUTE32(SEL, KVV)                                                    \
  do {                                                                         \
    f32x16 sv0, sv1;                                                           \
    _Pragma("unroll") for (int q2 = 0; q2 < 4; ++q2) {                         \
      f32x4 mk0 = *(const f32x4*)(lds + 32768 + ((KVV) + 8 * q2 + 4 * b5) * 4);\
      f32x4 mk1 = *(const f32x4*)(lds + 32768 + ((KVV) + 32 + 8 * q2 + 4 * b5) * 4);\
      _Pragma("unroll") for (int i = 0; i < 4; ++i) {                          \
        sv0[q2 * 4 + i] = mk0[i];                                              \
        sv1[q2 * 4 + i] = mk1[i];                                              \
      }                                                                        \
    }                                                                          \
    _Pragma("unroll") for (int kb = 0; kb < 4; ++kb) {                         \
      bf16x8 kf0 = *(const bf16x8*)(rowb + (SEL) * 8192 + gg[kb]);             \
      sv0 = __builtin_amdgcn_mfma_f32_32x32x16_bf16(kf0, qb[kb], sv0, 0, 0, 0);\
      bf16x8 kf1 = *(const bf16x8*)(rowb + (SEL) * 8192 + 4096 + gg[kb]);      \
      sv1 = __builtin_amdgcn_mfma_f32_32x32x16_bf16(kf1, qb[kb], sv1, 0, 0, 0);\
    }                                                                          \
    float rs = 0.f;                                                            \
    _Pragma("unroll") for (int i = 0; i < 16; ++i) {                           \
      sv0[i] = exp2f(sv0[i]);                                                  \
      sv1[i] = exp2f(sv1[i]);                                                  \
      rs += sv0[i] + sv1[i];                                                   \
    }                                                                          \
    lrun += rs;                                                                \
    bf16x8 pa[4];                                                              \
    _Pragma("unroll") for (int c = 0; c < 2; ++c)                              \
      _Pragma("unroll") for (int j = 0; j < 2; ++j) {                          \
        u16x8 t;                                                               \
        _Pragma("unroll") for (int e = 0; e < 8; ++e) {                        \
          float pv = (c == 0) ? sv0[8 * j + e] : sv1[8 * j + e];               \
          t[e] = __builtin_bit_cast(u16, (__bf16)pv);                          \
        }                                                                      \
        pa[c * 2 + j] = __builtin_bit_cast(bf16x8, t);                         \
      }                                                                        \
    _Pragma("unroll") for (int m = 0; m < 4; ++m) {                            \
      u32x2 lo0 = *(const u32x2*)(rowb + 16384 + (SEL) * 8192 + vga[m]);       \
      u32x2 hi0 = *(const u32x2*)(rowb + 16384 + (SEL) * 8192 + vgb[m]);       \
      u32x4 vv0;                                                               \
      vv0[0] = lo0[0]; vv0[1] = lo0[1]; vv0[2] = hi0[0]; vv0[3] = hi0[1];      \
      oacc0 = __builtin_amdgcn_mfma_f32_32x32x16_bf16(                         \
          __builtin_bit_cast(bf16x8, vv0), pa[m], oacc0, 0, 0, 0);             \
      u32x2 lo1 = *(const u32x2*)(rowb + 16384 + (SEL) * 8192 + 4096 + vga[m]);\
      u32x2 hi1 = *(const u32x2*)(rowb + 16384 + (SEL) * 8192 + 4096 + vgb[m]);\
      u32x4 vv1;                                                               \
      vv1[0] = lo1[0]; vv1[1] = lo1[1]; vv1[2] = hi1[0]; vv1[3] = hi1[1];      \
      oacc1 = __builtin_amdgcn_mfma_f32_32x32x16_bf16(                         \
          __builtin_bit_cast(bf16x8, vv1), pa[m], oacc1, 0, 0, 0);             \
    }                                                                          \
  } while (0)

  // prologue: stage tile 0 + mask row
  STAGE(0, 0);
#pragma unroll
  for (int it = 0; it < 2; ++it) {
    int c = it * 256 + tid;
    __builtin_amdgcn_global_load_lds(GLB(mrowS + c * 4), LDSP(lds + 32768 + c * 16), 16, 0, 0);
  }
  __syncthreads();

  for (int kv = 0; kv < 2048; kv += 128) {
    if (kv + 64 < 2048) STAGE(1, kv + 64);
    COMPUTE32(0, kv);
    __syncthreads();
    if (kv + 128 < 2048) STAGE(0, kv + 128);
    COMPUTE32(1, kv + 64);
    __syncthreads();
  }

  // epilogue: combine partner halves of the denominator, write O
  float ltot = lrun + __shfl_xor(lrun, 32, 64);
  float linv = 1.0f / ltot;
  int t = q0 + wave * 32 + lam;
  u16* aorow = AO + ((size_t)b * 2048 + t) * 1024 + h * 64;
#pragma unroll
  for (int n = 0; n < 2; ++n) {
#pragma unroll
    for (int q2 = 0; q2 < 4; ++q2) {
      const f32x16& oc = n ? oacc1 : oacc0;
      bf16x2 lo = {(__bf16)(oc[q2 * 4 + 0] * linv), (__bf16)(oc[q2 * 4 + 1] * linv)};
      bf16x2 hi = {(__bf16)(oc[q2 * 4 + 2] * linv), (__bf16)(oc[q2 * 4 + 3] * linv)};
      u32x2 wv;
      wv[0] = __builtin_bit_cast(u32, lo);
      wv[1] = __builtin_bit_cast(u32, hi);
      int d0 = 32 * n + 8 * q2 + 4 * b5;
      *(u32x2*)(aorow + d0) = wv;
    }
  }
#undef STAGE
#undef COMPUTE32
}

// ---------------- launch ----------------
extern "C" void kernel_launch(void* const* d_in, const int* in_sizes, int n_in,
                              void* d_out, int out_size, void* d_ws, size_t ws_size,
                              hipStream_t stream) {
  const float* x     = (const float*)d_in[0];
  const float* mask  = (const float*)d_in[1];
  const float* w_in  = (const float*)d_in[2];
  const float* b_in  = (const float*)d_in[3];
  const float* w_out = (const float*)d_in[4];
  const float* b_out = (const float*)d_in[5];
  float* out = (float*)d_out;

  u16* xbf  = (u16*)d_ws;
  u16* wbf  = xbf  + (size_t)8192 * 1024;
  u16* owbf = wbf  + (size_t)3072 * 1024;
  u16* qkvp = owbf + (size_t)1024 * 1024;
  u16* vt   = qkvp + (size_t)3 * 8192 * 1024;
  u16* ao   = vt   + (size_t)8192 * 1024;
  float* mws = (float*)(ao + (size_t)8192 * 1024);

  cvt_bf16<<<4096, 256, 0, stream>>>(x, xbf, 8388608);
  cvt_bf16<<<1536, 256, 0, stream>>>(w_in, wbf, 3145728);
  cvt_bf16<<<512, 256, 0, stream>>>(w_out, owbf, 1048576);
  scale_mask<<<32, 256, 0, stream>>>(mask, mws, 8192);

  gemm_bt<<<dim3(24, 64), 256, 0, stream>>>(xbf, wbf, b_in, nullptr, qkvp,
                                            8192, 3072, 1024, 1);
  transv<<<dim3(32, 64), 256, 0, stream>>>(qkvp + (size_t)2 * 8192 * 1024, vt);
  attn_fwd<<<1024, 256, 0, stream>>>(qkvp, qkvp + (size_t)8192 * 1024,
                                     vt, mws, ao);
  gemm_bt<<<dim3(8, 64), 256, 0, stream>>>(ao, owbf, b_out, out, nullptr,
                                           8192, 1024, 1024, 0);
}

// Round 9
// 211.255 us; speedup vs baseline: 1.5188x; 1.0353x over previous
//
#include <hip/hip_runtime.h>
#include <hip/hip_bf16.h>
#include <cstdint>

typedef unsigned short u16;
typedef unsigned int   u32;
typedef __bf16  bf16x8 __attribute__((ext_vector_type(8)));
typedef __bf16  bf16x2 __attribute__((ext_vector_type(2)));
typedef float   f32x4  __attribute__((ext_vector_type(4)));
typedef float   f32x16 __attribute__((ext_vector_type(16)));
typedef unsigned short u16x8 __attribute__((ext_vector_type(8)));
typedef unsigned int   u32x2 __attribute__((ext_vector_type(2)));
typedef unsigned int   u32x4 __attribute__((ext_vector_type(4)));

#define GLB(p) ((__attribute__((address_space(1))) void*)(p))
#define LDSP(p) ((__attribute__((address_space(3))) void*)(p))

__device__ __forceinline__ u16 f2bf(float f) {
  u32 u = __builtin_bit_cast(u32, f);
  u32 r = u + 0x7fffu + ((u >> 16) & 1u);
  return (u16)(r >> 16);
}

// ---------------- f32 -> bf16 convert (8 elems/thread) ----------------
__global__ __launch_bounds__(256) void cvt_bf16(const float* __restrict__ in,
                                                u16* __restrict__ out, int n) {
  int i = (blockIdx.x * 256 + threadIdx.x) * 8;
  if (i >= n) return;
  f32x4 a = *(const f32x4*)(in + i);
  f32x4 b = *(const f32x4*)(in + i + 4);
  u16x8 o;
#pragma unroll
  for (int j = 0; j < 4; ++j) { o[j] = f2bf(a[j]); o[4 + j] = f2bf(b[j]); }
  *(u16x8*)(out + i) = o;
}

// -------- mask -> weights: w = exp2(mask*log2e - 8); wf f32 + permuted bf16 ----
// perm within each 16: swap bits 2<->3 (involution) to match P C-layout key order
__global__ __launch_bounds__(256) void scale_mask(const float* __restrict__ in,
                                                  float* __restrict__ wf,
                                                  u16* __restrict__ wpb, int n) {
  int i = blockIdx.x * 256 + threadIdx.x;
  if (i >= n) return;
  float m = in[i] * 1.4426950408889634f - 8.0f;
  float w = exp2f(m);
  wf[i] = w;
  int l = i & 15;
  int lp = (l & 3) | ((l & 4) << 1) | ((l & 8) >> 1);
  wpb[(i & ~15) | lp] = f2bf(w);
}

// ---------------- GEMM C = A * B^T (+bias), bf16 MFMA ----------------
// mode 1: pack qkv [sect][b][h][t][d]; Q section pre-scaled by 1/sqrt(d)*log2e
__global__ __launch_bounds__(256) void gemm_bt(
    const u16* __restrict__ A, const u16* __restrict__ B,
    const float* __restrict__ bias,
    float* __restrict__ Cf, u16* __restrict__ Cq,
    int M, int N, int K, int mode) {
  __shared__ char lds[32768];
  char* ldsA = lds;
  char* ldsB = lds + 16384;
  const int tid  = threadIdx.x;
  const int lane = tid & 63;
  const int wave = tid >> 6;
  const int m0 = blockIdx.y * 128;
  const int n0 = blockIdx.x * 128;
  const int wr = (wave >> 1) * 64;
  const int wc = (wave & 1) * 64;

  const u16* gA[4];
  const u16* gB[4];
#pragma unroll
  for (int it = 0; it < 4; ++it) {
    int c  = it * 256 + tid;
    int r  = c >> 3;
    int ch = (c & 7) ^ (r & 7);
    gA[it] = A + (size_t)(m0 + r) * K + ch * 8;
    gB[it] = B + (size_t)(n0 + r) * K + ch * 8;
  }

  f32x4 acc[4][4] = {};

  const int arow  = wr + (lane & 15);
  const int brow  = wc + (lane & 15);
  const int kswz  = (lane & 7) << 4;
  const int kbyte = (lane >> 4) * 16;

  for (int kk = 0; kk < K; kk += 64) {
    __syncthreads();
#pragma unroll
    for (int it = 0; it < 4; ++it) {
      int c = it * 256 + tid;
      __builtin_amdgcn_global_load_lds(GLB(gA[it] + kk), LDSP(ldsA + c * 16), 16, 0, 0);
      __builtin_amdgcn_global_load_lds(GLB(gB[it] + kk), LDSP(ldsB + c * 16), 16, 0, 0);
    }
    __syncthreads();
#pragma unroll
    for (int s = 0; s < 2; ++s) {
      bf16x8 af[4], bfr[4];
#pragma unroll
      for (int i = 0; i < 4; ++i)
        af[i] = *(const bf16x8*)(ldsA + (arow + i * 16) * 128 + ((kbyte + s * 64) ^ kswz));
#pragma unroll
      for (int j = 0; j < 4; ++j)
        bfr[j] = *(const bf16x8*)(ldsB + (brow + j * 16) * 128 + ((kbyte + s * 64) ^ kswz));
#pragma unroll
      for (int i = 0; i < 4; ++i)
#pragma unroll
        for (int j = 0; j < 4; ++j)
          acc[i][j] = __builtin_amdgcn_mfma_f32_16x16x32_bf16(af[i], bfr[j], acc[i][j], 0, 0, 0);
    }
  }

  const int r0 = m0 + wr + (lane >> 4) * 4;
  const int c0 = n0 + wc + (lane & 15);
#pragma unroll
  for (int i = 0; i < 4; ++i) {
#pragma unroll
    for (int j = 0; j < 4; ++j) {
      int col  = c0 + j * 16;
      float bv = bias[col];
#pragma unroll
      for (int r = 0; r < 4; ++r) {
        int row = r0 + i * 16 + r;
        float v = acc[i][j][r] + bv;
        if (mode == 0) {
          Cf[(size_t)row * N + col] = v;
        } else {
          if (col < 1024) v *= 0.18033688011112042f;  // Q pre-scale: log2e/sqrt(64)
          int sect = col >> 10, rem = col & 1023;
          int hh = rem >> 6, dd = rem & 63;
          int bb = row >> 11, tt = row & 2047;
          Cq[((((size_t)sect * 4 + bb) * 16 + hh) * 2048 + tt) * 64 + dd] = f2bf(v);
        }
      }
    }
  }
}

// ---- V transpose + weight-fold + key-perm: [bh][t][d] -> [bh][d][t'] ----
// V'[d][16c + k'] = w[t0+16c+l(k')] * V[t0+16c+l(k')][d],  l = swap bits 2<->3
__global__ __launch_bounds__(256) void transv(const u16* __restrict__ Vp,
                                              u16* __restrict__ Vt,
                                              const float* __restrict__ wf) {
  __shared__ u16 tl[64][68];
  const int tid = threadIdx.x;
  const int bh  = blockIdx.y;
  const int b   = bh >> 4;
  const int t0  = blockIdx.x * 64;
  const u16* src = Vp + ((size_t)bh * 2048 + t0) * 64;
  const float* wrow = wf + (size_t)b * 2048 + t0;
#pragma unroll
  for (int it = 0; it < 2; ++it) {
    int c = it * 256 + tid;
    int r = c >> 3, ch = c & 7;
    u16x8 v = *(const u16x8*)(src + r * 64 + ch * 8);
    float wv = wrow[r];
#pragma unroll
    for (int j = 0; j < 8; ++j) {
      float f = __builtin_bit_cast(float, ((u32)v[j]) << 16) * wv;
      tl[r][ch * 8 + j] = f2bf(f);
    }
  }
  __syncthreads();
  u16* dst = Vt + (size_t)bh * 64 * 2048 + t0;
  const int kmap[2][8] = {{0, 1, 2, 3, 8, 9, 10, 11}, {4, 5, 6, 7, 12, 13, 14, 15}};
#pragma unroll
  for (int it = 0; it < 2; ++it) {
    int c = it * 256 + tid;
    int d = c >> 3, ch = c & 7;
    int base = 16 * (ch >> 1);
    u16x8 v;
#pragma unroll
    for (int j = 0; j < 8; ++j) v[j] = tl[base + kmap[ch & 1][j]][d];
    *(u16x8*)(dst + (size_t)d * 2048 + ch * 8) = v;
  }
}

// -------- flash attention fwd: 32x32 MFMA, in-register P, mfma denominator ----
// Qp: [bh][t][64] bf16 PRE-SCALED by log2e/8; Kp: [bh][t][64]
// Vt: [bh][64][t'] bf16 = w-folded, key-permuted V^T; wpb: [b][t'] bf16 permuted w
// AO: [b*T][1024] bf16
// LDS: K dbuf @0 (2x8K), V dbuf @16384 (2x8K), wperm row @32768 (4K)
__global__ __launch_bounds__(256, 4) void attn_fwd(
    const u16* __restrict__ Qp, const u16* __restrict__ Kp,
    const u16* __restrict__ Vt, const u16* __restrict__ wpb,
    u16* __restrict__ AO) {
  __shared__ char lds[36864];
  const int tid  = threadIdx.x;
  const int lane = tid & 63;
  const int wave = tid >> 6;
  const int lam  = lane & 31;       // q-col within wave's 32 rows
  const int b5   = lane >> 5;       // half-wave selector

  // XCD-aware swizzle: each XCD owns 8 heads (K/V L2-resident)
  const int s  = blockIdx.x;
  const int w  = (s & 7) * 128 + (s >> 3);
  const int qt = w & 15;
  const int bh = w >> 4;
  const int b  = bh >> 4;
  const int h  = bh & 15;
  const int q0 = qt * 128;

  const u16* Qbase = Qp + ((size_t)bh * 2048 + q0) * 64;
  const u16* Kbase = Kp + (size_t)bh * 2048 * 64;
  const u16* Vbase = Vt + (size_t)bh * 64 * 2048;
  const u16* wrow  = wpb + (size_t)b * 2048;

  // staging sources (pre-swizzled: physical granule c&7 holds logical (c&7)^(r&7))
  const u16* gK[2];
  const u16* gV[2];
  int ldso[2];
#pragma unroll
  for (int it = 0; it < 2; ++it) {
    int c = it * 256 + tid;
    int r = c >> 3;
    int ch = (c & 7) ^ (r & 7);
    gK[it] = Kbase + (size_t)r * 64 + ch * 8;
    gV[it] = Vbase + (size_t)r * 2048 + ch * 8;
    ldso[it] = c * 16;
  }

#define STAGE(SEL, KVV)                                                        \
  do {                                                                         \
    _Pragma("unroll") for (int it = 0; it < 2; ++it) {                         \
      __builtin_amdgcn_global_load_lds(GLB(gK[it] + (size_t)(KVV) * 64),       \
                                       LDSP(lds + (SEL) * 8192 + ldso[it]), 16, 0, 0); \
      __builtin_amdgcn_global_load_lds(GLB(gV[it] + (KVV)),                    \
                                       LDSP(lds + 16384 + (SEL) * 8192 + ldso[it]), 16, 0, 0); \
    }                                                                          \
  } while (0)

  // Q fragments from global: qb[kb] = Q[qrow][kb*16 + b5*8 .. +7]
  bf16x8 qb[4];
  {
    int qrow = wave * 32 + lam;
#pragma unroll
    for (int kb = 0; kb < 4; ++kb)
      qb[kb] = __builtin_bit_cast(bf16x8,
               *(const u16x8*)(Qbase + qrow * 64 + kb * 16 + b5 * 8));
  }

  f32x16 oacc0 = {}, oacc1 = {};
  f32x16 lsum = {};          // denominator accumulator (all regs equal)
  const f32x16 z16 = {};     // hoisted zero C-operand for QK^T

  // b128 read granules: logical granule (2j|b5), row = lam (K and permuted-V)
  int gg[4];
#pragma unroll
  for (int j = 0; j < 4; ++j) gg[j] = (((j << 1) | b5) ^ (lam & 7)) << 4;
  const char* rowb = lds + lam * 128;

#define COMPUTE32(SEL, KVV)                                                    \
  do {                                                                         \
    f32x16 sv0, sv1;                                                           \
    {                                                                          \
      bf16x8 kf0 = *(const bf16x8*)(rowb + (SEL) * 8192 + gg[0]);              \
      sv0 = __builtin_amdgcn_mfma_f32_32x32x16_bf16(kf0, qb[0], z16, 0, 0, 0); \
      bf16x8 kf1 = *(const bf16x8*)(rowb + (SEL) * 8192 + 4096 + gg[0]);       \
      sv1 = __builtin_amdgcn_mfma_f32_32x32x16_bf16(kf1, qb[0], z16, 0, 0, 0); \
    }                                                                          \
    _Pragma("unroll") for (int kb = 1; kb < 4; ++kb) {                         \
      bf16x8 kf0 = *(const bf16x8*)(rowb + (SEL) * 8192 + gg[kb]);             \
      sv0 = __builtin_amdgcn_mfma_f32_32x32x16_bf16(kf0, qb[kb], sv0, 0, 0, 0);\
      bf16x8 kf1 = *(const bf16x8*)(rowb + (SEL) * 8192 + 4096 + gg[kb]);      \
      sv1 = __builtin_amdgcn_mfma_f32_32x32x16_bf16(kf1, qb[kb], sv1, 0, 0, 0);\
    }                                                                          \
    _Pragma("unroll") for (int i = 0; i < 16; ++i) {                           \
      sv0[i] = exp2f(sv0[i]);                                                  \
      sv1[i] = exp2f(sv1[i]);                                                  \
    }                                                                          \
    bf16x8 pa[4];                                                              \
    _Pragma("unroll") for (int c = 0; c < 2; ++c)                              \
      _Pragma("unroll") for (int j = 0; j < 2; ++j) {                          \
        u16x8 t;                                                               \
        _Pragma("unroll") for (int e = 0; e < 8; ++e) {                        \
          float pv = (c == 0) ? sv0[8 * j + e] : sv1[8 * j + e];               \
          t[e] = __builtin_bit_cast(u16, (__bf16)pv);                          \
        }                                                                      \
        pa[c * 2 + j] = __builtin_bit_cast(bf16x8, t);                         \
      }                                                                        \
    _Pragma("unroll") for (int m = 0; m < 4; ++m) {                            \
      bf16x8 wfr = *(const bf16x8*)(lds + 32768 + ((KVV) + 16 * m) * 2 + 16 * b5); \
      lsum = __builtin_amdgcn_mfma_f32_32x32x16_bf16(wfr, pa[m], lsum, 0, 0, 0); \
      bf16x8 vf0 = *(const bf16x8*)(rowb + 16384 + (SEL) * 8192 + gg[m]);      \
      oacc0 = __builtin_amdgcn_mfma_f32_32x32x16_bf16(vf0, pa[m], oacc0, 0, 0, 0); \
      bf16x8 vf1 = *(const bf16x8*)(rowb + 16384 + (SEL) * 8192 + 4096 + gg[m]); \
      oacc1 = __builtin_amdgcn_mfma_f32_32x32x16_bf16(vf1, pa[m], oacc1, 0, 0, 0); \
    }                                                                          \
  } while (0)

  // prologue: stage tile 0 + permuted weight row
  STAGE(0, 0);
  __builtin_amdgcn_global_load_lds(GLB(wrow + tid * 8), LDSP(lds + 32768 + tid * 16), 16, 0, 0);
  __syncthreads();

  for (int kv = 0; kv < 2048; kv += 128) {
    if (kv + 64 < 2048) STAGE(1, kv + 64);
    COMPUTE32(0, kv);
    __syncthreads();
    if (kv + 128 < 2048) STAGE(0, kv + 128);
    COMPUTE32(1, kv + 64);
    __syncthreads();
  }

  // epilogue: denominator is lane-local in lsum (all regs equal)
  float linv = 1.0f / lsum[0];
  int t = q0 + wave * 32 + lam;
  u16* aorow = AO + ((size_t)b * 2048 + t) * 1024 + h * 64;
#pragma unroll
  for (int n = 0; n < 2; ++n) {
#pragma unroll
    for (int q2 = 0; q2 < 4; ++q2) {
      const f32x16& oc = n ? oacc1 : oacc0;
      bf16x2 lo = {(__bf16)(oc[q2 * 4 + 0] * linv), (__bf16)(oc[q2 * 4 + 1] * linv)};
      bf16x2 hi = {(__bf16)(oc[q2 * 4 + 2] * linv), (__bf16)(oc[q2 * 4 + 3] * linv)};
      u32x2 wv;
      wv[0] = __builtin_bit_cast(u32, lo);
      wv[1] = __builtin_bit_cast(u32, hi);
      int d0 = 32 * n + 8 * q2 + 4 * b5;
      *(u32x2*)(aorow + d0) = wv;
    }
  }
#undef STAGE
#undef COMPUTE32
}

// ---------------- launch ----------------
extern "C" void kernel_launch(void* const* d_in, const int* in_sizes, int n_in,
                              void* d_out, int out_size, void* d_ws, size_t ws_size,
                              hipStream_t stream) {
  const float* x     = (const float*)d_in[0];
  const float* mask  = (const float*)d_in[1];
  const float* w_in  = (const float*)d_in[2];
  const float* b_in  = (const float*)d_in[3];
  const float* w_out = (const float*)d_in[4];
  const float* b_out = (const float*)d_in[5];
  float* out = (float*)d_out;

  u16* xbf  = (u16*)d_ws;
  u16* wbf  = xbf  + (size_t)8192 * 1024;
  u16* owbf = wbf  + (size_t)3072 * 1024;
  u16* qkvp = owbf + (size_t)1024 * 1024;
  u16* vt   = qkvp + (size_t)3 * 8192 * 1024;
  u16* ao   = vt   + (size_t)8192 * 1024;
  float* wf = (float*)(ao + (size_t)8192 * 1024);
  u16* wpb  = (u16*)(wf + 8192);

  cvt_bf16<<<4096, 256, 0, stream>>>(x, xbf, 8388608);
  cvt_bf16<<<1536, 256, 0, stream>>>(w_in, wbf, 3145728);
  cvt_bf16<<<512, 256, 0, stream>>>(w_out, owbf, 1048576);
  scale_mask<<<32, 256, 0, stream>>>(mask, wf, wpb, 8192);

  gemm_bt<<<dim3(24, 64), 256, 0, stream>>>(xbf, wbf, b_in, nullptr, qkvp,
                                            8192, 3072, 1024, 1);
  transv<<<dim3(32, 64), 256, 0, stream>>>(qkvp + (size_t)2 * 8192 * 1024, vt, wf);
  attn_fwd<<<1024, 256, 0, stream>>>(qkvp, qkvp + (size_t)8192 * 1024,
                                     vt, wpb, ao);
  gemm_bt<<<dim3(8, 64), 256, 0, stream>>>(ao, owbf, b_out, out, nullptr,
                                           8192, 1024, 1024, 0);
}